// Round 7
// baseline (750.340 us; speedup 1.0000x reference)
//
#include <hip/hip_runtime.h>
#include <math.h>

#define D_MODEL 1024
#define N_TOK   8192
#define SEQ_L   1024
#define N_HEAD  16
#define HEAD_D  64
#define FF_DIM  4096

typedef __attribute__((ext_vector_type(8))) short bf16x8;   // 8 bf16 = 4 VGPRs
typedef __attribute__((ext_vector_type(4))) short short4v;
typedef __attribute__((ext_vector_type(2))) int  int2v;
typedef __attribute__((ext_vector_type(4))) float f32x4;

#define MFMA16(a, b, c) __builtin_amdgcn_mfma_f32_16x16x32_bf16((a), (b), (c), 0, 0, 0)

// async global->LDS, 16B per lane; LDS dest = wave-uniform base + lane*16
#define GLD16(gp, lp) __builtin_amdgcn_global_load_lds(                      \
    (const __attribute__((address_space(1))) void*)(gp),                     \
    (__attribute__((address_space(3))) void*)(lp), 16, 0, 0)

#if defined(__has_builtin)
#if __has_builtin(__builtin_amdgcn_exp2f)
#define EXP2F(x) __builtin_amdgcn_exp2f(x)
#else
#define EXP2F(x) exp2f(x)
#endif
#else
#define EXP2F(x) exp2f(x)
#endif

__device__ __forceinline__ short f2bf(float f) {   // fp32 -> bf16 (RNE)
    unsigned u = __float_as_uint(f);
    u += 0x7fffu + ((u >> 16) & 1u);
    return (short)(u >> 16);
}

// pack two fp32 -> two bf16 (round-nearest-up) in one v_perm
__device__ __forceinline__ int pack2bf(float a, float b) {
    unsigned ua = __float_as_uint(a) + 0x8000u;
    unsigned ub = __float_as_uint(b) + 0x8000u;
    return __builtin_amdgcn_perm(ub, ua, 0x07060302u);
}

// ---------------------------------------------------------------------------
// LayerNorm fp32 -> bf16. One block (256 thr) per token.
// ---------------------------------------------------------------------------
__global__ __launch_bounds__(256) void ln_kernel(const float* __restrict__ x,
                                                 const float* __restrict__ g,
                                                 const float* __restrict__ b,
                                                 short* __restrict__ o)
{
    int t = blockIdx.x;
    const float* xr = x + (size_t)t * D_MODEL;
    short* orow = o + (size_t)t * D_MODEL;
    float vals[4];
    float lsum = 0.f, lsq = 0.f;
#pragma unroll
    for (int i = 0; i < 4; i++) {
        float v = xr[threadIdx.x + i * 256];
        vals[i] = v; lsum += v; lsq += v * v;
    }
#pragma unroll
    for (int off = 32; off > 0; off >>= 1) {
        lsum += __shfl_down(lsum, off);
        lsq  += __shfl_down(lsq,  off);
    }
    __shared__ float red[8];
    int wid = threadIdx.x >> 6, lane = threadIdx.x & 63;
    if (lane == 0) { red[wid] = lsum; red[4 + wid] = lsq; }
    __syncthreads();
    if (threadIdx.x == 0) {
        red[0] = red[0] + red[1] + red[2] + red[3];
        red[4] = red[4] + red[5] + red[6] + red[7];
    }
    __syncthreads();
    float mean = red[0] * (1.f / D_MODEL);
    float var  = red[4] * (1.f / D_MODEL) - mean * mean;
    float inv  = rsqrtf(var + 1e-5f);
#pragma unroll
    for (int i = 0; i < 4; i++) {
        int c = threadIdx.x + i * 256;
        orow[c] = f2bf((vals[i] - mean) * inv * g[c] + b[c]);
    }
}

// ---------------------------------------------------------------------------
// mask int -> fp32 additive (log2-domain): 0 or -1e30
// ---------------------------------------------------------------------------
__global__ __launch_bounds__(256) void mask_kernel(const int* __restrict__ m,
                                                   float* __restrict__ fm)
{
    int i = blockIdx.x * 256 + threadIdx.x;
    fm[i] = (m[i] > 0) ? 0.f : -1e30f;
}

// ---------------------------------------------------------------------------
// Fused weight prep: all six W [K,N] fp32 -> W^T [N,K] bf16 transposes in
// ONE dispatch. Block id ranges select the region; 32x32 tiles.
// ---------------------------------------------------------------------------
__global__ __launch_bounds__(256) void prep_kernel(
    const float* __restrict__ wq, const float* __restrict__ wk,
    const float* __restrict__ wv, const float* __restrict__ wo,
    const float* __restrict__ w1, const float* __restrict__ w2,
    short* __restrict__ wqkvt, short* __restrict__ wot,
    short* __restrict__ w1t,  short* __restrict__ w2t)
{
    int id = blockIdx.x;
    const float* src; short* dst; int R, C, tloc, csh;
    if (id < 4096) {
        int wsel = id >> 10; tloc = id & 1023; R = 1024; C = 1024; csh = 5;
        src = (wsel == 0) ? wq : (wsel == 1) ? wk : (wsel == 2) ? wv : wo;
        dst = (wsel == 3) ? wot : (wqkvt + (size_t)wsel * 1024 * 1024);
    } else if (id < 8192) {
        tloc = id - 4096; R = 1024; C = 4096; csh = 7; src = w1; dst = w1t;
    } else {
        tloc = id - 8192; R = 4096; C = 1024; csh = 5; src = w2; dst = w2t;
    }
    int ty = tloc >> csh, tx = tloc & ((1 << csh) - 1);
    int r0 = ty * 32, c0 = tx * 32;
    __shared__ float t[32][33];
    int tid = threadIdx.x;
#pragma unroll
    for (int i = 0; i < 4; i++) {
        int idx = i * 256 + tid;
        int r = idx >> 5, c = idx & 31;
        t[r][c] = src[(size_t)(r0 + r) * C + c0 + c];
    }
    __syncthreads();
#pragma unroll
    for (int i = 0; i < 4; i++) {
        int idx = i * 256 + tid;
        int rr = idx >> 5, cc = idx & 31;
        dst[(size_t)(c0 + rr) * R + r0 + cc] = f2bf(t[cc][rr]);
    }
}

// ---------------------------------------------------------------------------
// bf16 MFMA GEMM, BK=64, chunk-major LDS (conflict-free ds_read_b128).
// C[M,N] = epilogue(A[M,K] @ Bt[N,K]^T). 128x128 tile, 256 thr = 4 waves,
// each wave 64x64 via 4x4 16x16x32 frags, 2 k-steps per staged tile.
// LDS slot s (16B) = kchunk*128 + row; staging call cid in [0,16):
// kc=cid>>1, rows (cid&1)*64 + lane (per-lane strided global gather).
// Frag read: slot ((ko*4+quad)*128 + row) -> banks sweep uniformly.
// C/D layout: col=lane&15, row=quad*4+reg.
// Modes: qkv=1 (fused QKV, V transposed store) / bias+gelu+resid, f32/bf16.
// ---------------------------------------------------------------------------
__global__ __launch_bounds__(256) void gemm_bf16(
    const short* __restrict__ A, int lda,
    const short* __restrict__ Bt, int ldb,
    const float* __restrict__ bias,
    const float* __restrict__ bias2,
    const float* __restrict__ bias3,
    const float* __restrict__ resid,
    float* __restrict__ Cf, short* __restrict__ Cb, short* __restrict__ Cvt,
    int ldc, int K, int act, int qkv)
{
    __shared__ __align__(16) short sA[128 * 64];   // 16KB, chunk-major
    __shared__ __align__(16) short sB[128 * 64];   // 16KB, chunk-major
    const int tid = threadIdx.x;
    const int lane = tid & 63, wave = tid >> 6;
    const int quad = lane >> 4, l15 = lane & 15;
    const int bm = blockIdx.y * 128, bn = blockIdx.x * 128;
    const int wm = (wave >> 1) * 64, wn = (wave & 1) * 64;

    f32x4 acc[4][4];
#pragma unroll
    for (int i = 0; i < 4; i++)
#pragma unroll
        for (int j = 0; j < 4; j++) acc[i][j] = (f32x4){0.f, 0.f, 0.f, 0.f};

    for (int k0 = 0; k0 < K; k0 += 64) {
        __syncthreads();
        // stage A-tile + B-tile: 4 A-calls + 4 B-calls per wave
#pragma unroll
        for (int j = 0; j < 4; j++) {
            int cid = wave * 4 + j;               // 0..15
            int kc = cid >> 1, rb0 = (cid & 1) << 6;
            GLD16(A  + (size_t)(bm + rb0 + lane) * lda + k0 + kc * 8,
                  &sA[cid * 512]);
            GLD16(Bt + (size_t)(bn + rb0 + lane) * ldb + k0 + kc * 8,
                  &sB[cid * 512]);
        }
        __syncthreads();
#pragma unroll
        for (int ko = 0; ko < 2; ko++) {
            bf16x8 af[4], bfr[4];
#pragma unroll
            for (int mt = 0; mt < 4; mt++)
                af[mt] = *(const bf16x8*)&sA[((ko * 4 + quad) * 128 + wm + mt * 16 + l15) * 8];
#pragma unroll
            for (int nt = 0; nt < 4; nt++)
                bfr[nt] = *(const bf16x8*)&sB[((ko * 4 + quad) * 128 + wn + nt * 16 + l15) * 8];
#pragma unroll
            for (int mt = 0; mt < 4; mt++)
#pragma unroll
                for (int nt = 0; nt < 4; nt++)
                    acc[mt][nt] = MFMA16(af[mt], bfr[nt], acc[mt][nt]);
        }
    }

#pragma unroll
    for (int mt = 0; mt < 4; mt++)
#pragma unroll
        for (int nt = 0; nt < 4; nt++) {
            int row0 = bm + wm + mt * 16 + quad * 4;
            int col  = bn + wn + nt * 16 + l15;
            if (qkv) {
                int seg = col >> 10, cloc = col & 1023;
                const float* bp = (seg == 0) ? bias : (seg == 1) ? bias2 : bias3;
                float bval = bp[cloc];
                if (seg == 2) {
                    // V transposed store: page=(b*H+h)*64+d, index = seq pos
                    int bb = row0 >> 10, l0 = row0 & 1023;
                    size_t page = (size_t)(bb * N_HEAD + (cloc >> 6)) * HEAD_D + (cloc & 63);
                    short4v pk = { f2bf(acc[mt][nt][0] + bval), f2bf(acc[mt][nt][1] + bval),
                                   f2bf(acc[mt][nt][2] + bval), f2bf(acc[mt][nt][3] + bval) };
                    *(short4v*)&Cvt[page * SEQ_L + l0] = pk;
                } else {
                    short* dst = Cb + (size_t)seg * ((size_t)N_TOK * D_MODEL);
#pragma unroll
                    for (int r = 0; r < 4; r++)
                        dst[(size_t)(row0 + r) * D_MODEL + cloc] = f2bf(acc[mt][nt][r] + bval);
                }
            } else {
#pragma unroll
                for (int r = 0; r < 4; r++) {
                    int row = row0 + r;
                    float v = acc[mt][nt][r] + bias[col];
                    if (act) v = v / (1.f + __expf(-1.702f * v));   // quick_gelu
                    if (resid) v += resid[(size_t)row * ldc + col];
                    if (Cb) Cb[(size_t)row * ldc + col] = f2bf(v);
                    else    Cf[(size_t)row * ldc + col] = v;
                }
            }
        }
}

// ---------------------------------------------------------------------------
// Flash attention (unchanged from R6 — it works): bf16 MFMA, S^T form,
// K-step=128, m97-style LDS staging, log2-domain softmax, per-wave P slab.
// ---------------------------------------------------------------------------
__global__ __launch_bounds__(256) void attn_kernel(
    const short* __restrict__ Q, const short* __restrict__ Kb,
    const short* __restrict__ Vt, const float* __restrict__ fmask,
    short* __restrict__ O)
{
    __shared__ __align__(16) short sK[8192];        // 16KB: slot=kc*128+key
    __shared__ __align__(16) short sV[8192];        // 16KB: slot=kc2*64+d
    __shared__ __align__(16) short sP[4][16 * 136]; // per-wave [16 q][136]
    __shared__ __align__(16) float sAl[4][20];

    const int g = blockIdx.x;
    const int xcd = g & 7, slot = g >> 3;
    const int qt = slot & 15, bhl = slot >> 4;
    const int bh = xcd * 16 + bhl;
    const int b = bh >> 4, h = bh & 15;

    const int tid = threadIdx.x;
    const int wave = tid >> 6, lane = tid & 63;
    const int quad = lane >> 4, l15 = lane & 15;

    const int qbase = b * SEQ_L + qt * 64;
    const short* qp = Q + (size_t)(qbase + wave * 16 + l15) * D_MODEL + h * HEAD_D + quad * 8;
    bf16x8 qf0 = *(const bf16x8*)qp;
    bf16x8 qf1 = *(const bf16x8*)(qp + 32);

    const short* Kbh = Kb + (size_t)b * SEQ_L * D_MODEL + h * HEAD_D;
    const short* Vbh = Vt + (size_t)(b * N_HEAD + h) * HEAD_D * SEQ_L;
    const float* mk  = fmask + b * SEQ_L;

    f32x4 o4[4];
#pragma unroll
    for (int nt = 0; nt < 4; nt++) o4[nt] = (f32x4){0.f, 0.f, 0.f, 0.f};
    float mrow = -1e30f, lrow = 0.f;     // per-lane: q = l15 of this wave
    short* pslab = &sP[wave][0];         // per-wave private [16 q][136]
    const float CSC = 0.125f * 1.4426950408889634f;   // scale * log2(e)

    for (int kt = 0; kt < SEQ_L / 128; kt++) {
        __syncthreads();   // previous iter's frag reads done
        // ---- stage K-tile + V^T-tile (8 GLD16 per wave, no VGPR data) ----
#pragma unroll
        for (int j = 0; j < 4; j++) {
            int cid = wave * 4 + j;
            int kc = cid >> 1, key0 = (cid & 1) << 6;
            GLD16(Kbh + (size_t)(kt * 128 + key0 + lane) * D_MODEL + kc * 8,
                  &sK[cid * 512]);
            GLD16(Vbh + (size_t)lane * SEQ_L + kt * 128 + cid * 8,
                  &sV[cid * 512]);
        }
        __syncthreads();   // staging complete (vmcnt drained by barrier)

        // ---- mask loads (f32x4, indexed by key=row) ----
        f32x4 mkv[8];
#pragma unroll
        for (int sub = 0; sub < 8; sub++)
            mkv[sub] = *(const f32x4*)&mk[kt * 128 + sub * 16 + quad * 4];

        // ---- S^T = K·Q^T : D[m=key][n=q] ----
        f32x4 s[8];
#pragma unroll
        for (int sub = 0; sub < 8; sub++) {
            bf16x8 kf0 = *(const bf16x8*)&sK[(quad * 128 + sub * 16 + l15) * 8];
            bf16x8 kf1 = *(const bf16x8*)&sK[((quad + 4) * 128 + sub * 16 + l15) * 8];
            s[sub] = (f32x4){0.f, 0.f, 0.f, 0.f};
            s[sub] = MFMA16(kf0, qf0, s[sub]);
            s[sub] = MFMA16(kf1, qf1, s[sub]);
        }
        // ---- scale+mask in one FMA (log2 domain) ----
#pragma unroll
        for (int sub = 0; sub < 8; sub++)
#pragma unroll
            for (int r = 0; r < 4; r++) s[sub][r] = s[sub][r] * CSC + mkv[sub][r];

        // ---- per-lane max over 32 scores + 2 shuffles ----
        f32x4 mx4 = s[0];
#pragma unroll
        for (int sub = 1; sub < 8; sub++)
#pragma unroll
            for (int r = 0; r < 4; r++) mx4[r] = fmaxf(mx4[r], s[sub][r]);
        float pmax = fmaxf(fmaxf(mx4[0], mx4[1]), fmaxf(mx4[2], mx4[3]));
        pmax = fmaxf(pmax, __shfl_xor(pmax, 16));
        pmax = fmaxf(pmax, __shfl_xor(pmax, 32));
        float mnew = fmaxf(mrow, pmax);
        float alpha = EXP2F(mrow - mnew);
        mrow = mnew;
        if (quad == 0) sAl[wave][l15] = alpha;   // broadcast to O rows

        // ---- exp2 + pairwise pack + P writes ----
        float ls = 0.f;
#pragma unroll
        for (int sub = 0; sub < 8; sub++) {
            float p0 = EXP2F(s[sub][0] - mnew);
            float p1 = EXP2F(s[sub][1] - mnew);
            float p2 = EXP2F(s[sub][2] - mnew);
            float p3 = EXP2F(s[sub][3] - mnew);
            ls += (p0 + p1) + (p2 + p3);
            int2v pk = { pack2bf(p0, p1), pack2bf(p2, p3) };
            *(int2v*)&pslab[l15 * 136 + sub * 16 + quad * 4] = pk;
        }
        ls += __shfl_xor(ls, 16);
        ls += __shfl_xor(ls, 32);
        lrow = lrow * alpha + ls;

        // ---- rescale O by alpha (read per-row broadcast) ----
        f32x4 av = *(const f32x4*)&sAl[wave][quad * 4];
#pragma unroll
        for (int nt = 0; nt < 4; nt++)
#pragma unroll
            for (int r = 0; r < 4; r++) o4[nt][r] *= av[r];

        // ---- PV: P A-frags from slab, V B-frags from sV ----
        bf16x8 pf[4];
#pragma unroll
        for (int c = 0; c < 4; c++)
            pf[c] = *(const bf16x8*)&pslab[l15 * 136 + c * 32 + quad * 8];
#pragma unroll
        for (int nt = 0; nt < 4; nt++)
#pragma unroll
            for (int c = 0; c < 4; c++) {
                bf16x8 vfr = *(const bf16x8*)&sV[((c * 4 + quad) * 64 + nt * 16 + l15) * 8];
                o4[nt] = MFMA16(pf[c], vfr, o4[nt]);
            }
    }
    // final 1/l broadcast to O rows
    if (quad == 0) sAl[wave][l15] = 1.f / lrow;
    __syncthreads();
    f32x4 iv = *(const f32x4*)&sAl[wave][quad * 4];
#pragma unroll
    for (int nt = 0; nt < 4; nt++)
#pragma unroll
        for (int r = 0; r < 4; r++)
            O[(size_t)(qbase + wave * 16 + quad * 4 + r) * D_MODEL
              + h * HEAD_D + nt * 16 + l15] = f2bf(o4[nt][r] * iv[r]);
}

// ---------------------------------------------------------------------------
// Launch
// ---------------------------------------------------------------------------
extern "C" void kernel_launch(void* const* d_in, const int* in_sizes, int n_in,
                              void* d_out, int out_size, void* d_ws, size_t ws_size,
                              hipStream_t stream)
{
    const float* x     = (const float*)d_in[0];
    const int*   amask = (const int*)  d_in[1];
    const float* wq    = (const float*)d_in[2];
    const float* bq    = (const float*)d_in[3];
    const float* wk    = (const float*)d_in[4];
    const float* bk    = (const float*)d_in[5];
    const float* wv    = (const float*)d_in[6];
    const float* bv    = (const float*)d_in[7];
    const float* wo    = (const float*)d_in[8];
    const float* bo    = (const float*)d_in[9];
    const float* ln1s  = (const float*)d_in[10];
    const float* ln1b  = (const float*)d_in[11];
    const float* ln2s  = (const float*)d_in[12];
    const float* ln2b  = (const float*)d_in[13];
    const float* w1    = (const float*)d_in[14];
    const float* b1    = (const float*)d_in[15];
    const float* w2    = (const float*)d_in[16];
    const float* b2    = (const float*)d_in[17];
    float* out = (float*)d_out;

    // workspace layout (bytes; peak 104 MB, proven available)
    char* w = (char*)d_ws;
    short* wqkvt = (short*)(w + (size_t)0);          // [3072][1024] bf16, 6MB
    short* wot   = (short*)(w + ((size_t)6  << 20));
    short* w1t   = (short*)(w + ((size_t)8  << 20));
    short* w2t   = (short*)(w + ((size_t)16 << 20));
    short* hb    = (short*)(w + ((size_t)24 << 20)); // LN1 out, later LN2 out
    short* qb    = (short*)(w + ((size_t)40 << 20)); // qb,kbf contiguous:
    short* kbf   = (short*)(w + ((size_t)56 << 20)); //   16MB stride for qkv mode
    short* attnb = (short*)(w + ((size_t)72 << 20));
    short* vtb   = (short*)(w + ((size_t)88 << 20));
    short* ffb   = qb;   // q/k/vt dead by MLP1 (64 MB span 40..104)
    // fmask lives in the hb region (dead between QKV GEMM and LN2): 32KB
    float* fmaskb = (float*)(w + ((size_t)24 << 20));

    dim3 blk(256);

    // weight prep: all six transposes in ONE dispatch
    prep_kernel<<<dim3(12288), blk, 0, stream>>>(wq, wk, wv, wo, w1, w2,
                                                 wqkvt, wot, w1t, w2t);

    // 1) h = LN1(x) -> bf16
    ln_kernel<<<N_TOK, blk, 0, stream>>>(x, ln1s, ln1b, hb);

    // 2) fused QKV GEMM: writes qb, kbf, and V directly transposed (vtb)
    gemm_bf16<<<dim3(3 * D_MODEL / 128, N_TOK / 128), blk, 0, stream>>>(
        hb, 1024, wqkvt, 1024, bq, bk, bv, nullptr,
        nullptr, qb, vtb, 1024, 1024, 0, 1);

    // 2b) fp32 mask (into hb region — hb is dead until LN2 rewrites it)
    mask_kernel<<<dim3(8 * SEQ_L / 256), blk, 0, stream>>>(amask, fmaskb);

    // 3) flash attention -> attnb (bf16); 1-D grid, XCD swizzle inside
    attn_kernel<<<dim3(2048), blk, 0, stream>>>(qb, kbf, vtb, fmaskb, attnb);

    // 4) out = x + attn @ wo + bo  (fp32 out)
    gemm_bf16<<<dim3(D_MODEL / 128, N_TOK / 128), blk, 0, stream>>>(
        attnb, 1024, wot, 1024, bo, nullptr, nullptr, x,
        out, nullptr, nullptr, 1024, 1024, 0, 0);

    // 5) h = LN2(out) -> bf16
    ln_kernel<<<N_TOK, blk, 0, stream>>>(out, ln2s, ln2b, hb);

    // 6) MLP
    gemm_bf16<<<dim3(FF_DIM / 128, N_TOK / 128), blk, 0, stream>>>(
        hb, 1024, w1t, 1024, b1, nullptr, nullptr, nullptr,
        nullptr, ffb, nullptr, 4096, 1024, 1, 0);
    gemm_bf16<<<dim3(D_MODEL / 128, N_TOK / 128), blk, 0, stream>>>(
        ffb, 4096, w2t, 4096, b2, nullptr, nullptr, out,
        out, nullptr, nullptr, 1024, 4096, 0, 0);
}

// Round 9
// 588.782 us; speedup vs baseline: 1.2744x; 1.2744x over previous
//
#include <hip/hip_runtime.h>
#include <math.h>

#define D_MODEL 1024
#define N_TOK   8192
#define SEQ_L   1024
#define N_HEAD  16
#define HEAD_D  64
#define FF_DIM  4096

typedef __attribute__((ext_vector_type(8))) short bf16x8;   // 8 bf16 = 4 VGPRs
typedef __attribute__((ext_vector_type(4))) short short4v;
typedef __attribute__((ext_vector_type(2))) int  int2v;
typedef __attribute__((ext_vector_type(4))) float f32x4;

#define MFMA16(a, b, c) __builtin_amdgcn_mfma_f32_16x16x32_bf16((a), (b), (c), 0, 0, 0)

// async global->LDS, 16B per lane; LDS dest = wave-uniform base + lane*16
#define GLD16(gp, lp) __builtin_amdgcn_global_load_lds(                      \
    (const __attribute__((address_space(1))) void*)(gp),                     \
    (__attribute__((address_space(3))) void*)(lp), 16, 0, 0)

#if defined(__has_builtin)
#if __has_builtin(__builtin_amdgcn_exp2f)
#define EXP2F(x) __builtin_amdgcn_exp2f(x)
#else
#define EXP2F(x) exp2f(x)
#endif
#else
#define EXP2F(x) exp2f(x)
#endif

__device__ __forceinline__ short f2bf(float f) {   // fp32 -> bf16 (RNE)
    unsigned u = __float_as_uint(f);
    u += 0x7fffu + ((u >> 16) & 1u);
    return (short)(u >> 16);
}

// pack two fp32 -> two bf16 (round-nearest-up) in one v_perm
__device__ __forceinline__ int pack2bf(float a, float b) {
    unsigned ua = __float_as_uint(a) + 0x8000u;
    unsigned ub = __float_as_uint(b) + 0x8000u;
    return __builtin_amdgcn_perm(ub, ua, 0x07060302u);
}

// ---------------------------------------------------------------------------
// LayerNorm fp32 -> bf16. One block (256 thr) per token.
// ---------------------------------------------------------------------------
__global__ __launch_bounds__(256) void ln_kernel(const float* __restrict__ x,
                                                 const float* __restrict__ g,
                                                 const float* __restrict__ b,
                                                 short* __restrict__ o)
{
    int t = blockIdx.x;
    const float* xr = x + (size_t)t * D_MODEL;
    short* orow = o + (size_t)t * D_MODEL;
    float vals[4];
    float lsum = 0.f, lsq = 0.f;
#pragma unroll
    for (int i = 0; i < 4; i++) {
        float v = xr[threadIdx.x + i * 256];
        vals[i] = v; lsum += v; lsq += v * v;
    }
#pragma unroll
    for (int off = 32; off > 0; off >>= 1) {
        lsum += __shfl_down(lsum, off);
        lsq  += __shfl_down(lsq,  off);
    }
    __shared__ float red[8];
    int wid = threadIdx.x >> 6, lane = threadIdx.x & 63;
    if (lane == 0) { red[wid] = lsum; red[4 + wid] = lsq; }
    __syncthreads();
    if (threadIdx.x == 0) {
        red[0] = red[0] + red[1] + red[2] + red[3];
        red[4] = red[4] + red[5] + red[6] + red[7];
    }
    __syncthreads();
    float mean = red[0] * (1.f / D_MODEL);
    float var  = red[4] * (1.f / D_MODEL) - mean * mean;
    float inv  = rsqrtf(var + 1e-5f);
#pragma unroll
    for (int i = 0; i < 4; i++) {
        int c = threadIdx.x + i * 256;
        orow[c] = f2bf((vals[i] - mean) * inv * g[c] + b[c]);
    }
}

// ---------------------------------------------------------------------------
// Fused prep: six W [K,N] fp32 -> W^T [N,K] bf16 transposes + fp32 mask,
// all in ONE dispatch. Block id ranges select the job; 32x32 tiles.
// fmask target lives in d_out (free until the O-proj GEMM writes it).
// ---------------------------------------------------------------------------
__global__ __launch_bounds__(256) void prep_kernel(
    const float* __restrict__ wq, const float* __restrict__ wk,
    const float* __restrict__ wv, const float* __restrict__ wo,
    const float* __restrict__ w1, const float* __restrict__ w2,
    const int*   __restrict__ amask,
    short* __restrict__ wqkvt, short* __restrict__ wot,
    short* __restrict__ w1t,  short* __restrict__ w2t,
    float* __restrict__ fmask)
{
    int id = blockIdx.x;
    if (id >= 12288) {   // mask job: 32 blocks x 256 = 8192 entries
        int i = (id - 12288) * 256 + threadIdx.x;
        fmask[i] = (amask[i] > 0) ? 0.f : -1e30f;
        return;
    }
    const float* src; short* dst; int R, C, tloc, csh;
    if (id < 4096) {
        int wsel = id >> 10; tloc = id & 1023; R = 1024; C = 1024; csh = 5;
        src = (wsel == 0) ? wq : (wsel == 1) ? wk : (wsel == 2) ? wv : wo;
        dst = (wsel == 3) ? wot : (wqkvt + (size_t)wsel * 1024 * 1024);
    } else if (id < 8192) {
        tloc = id - 4096; R = 1024; C = 4096; csh = 7; src = w1; dst = w1t;
    } else {
        tloc = id - 8192; R = 4096; C = 1024; csh = 5; src = w2; dst = w2t;
    }
    int ty = tloc >> csh, tx = tloc & ((1 << csh) - 1);
    int r0 = ty * 32, c0 = tx * 32;
    __shared__ float t[32][33];
    int tid = threadIdx.x;
#pragma unroll
    for (int i = 0; i < 4; i++) {
        int idx = i * 256 + tid;
        int r = idx >> 5, c = idx & 31;
        t[r][c] = src[(size_t)(r0 + r) * C + c0 + c];
    }
    __syncthreads();
#pragma unroll
    for (int i = 0; i < 4; i++) {
        int idx = i * 256 + tid;
        int rr = idx >> 5, cc = idx & 31;
        dst[(size_t)(c0 + rr) * R + r0 + cc] = f2bf(t[cc][rr]);
    }
}

// ---------------------------------------------------------------------------
// bf16 MFMA GEMM, BK=64, XOR-swizzled LDS:
//   slot(row, chunk) = row*8 + (chunk ^ (row&7))      [16B slots]
// -> staging keeps 128B-segment global coalescing (lanes permute chunks
//    WITHIN a row segment) AND frag ds_read_b128 spreads bank groups.
//    2 barriers per 32 MFMAs (BK=64).
// Grid: 1-D, XCD row-panel swizzle (requires gy==64): xcd=id&7 owns rows
//    {xcd, xcd+8, ...}; A-row-tiles fetched by exactly one XCD.
// C/D layout: col=lane&15, row=quad*4+reg.
// Modes: qkv=1 (fused QKV, V transposed store) / bias+gelu+resid, f32/bf16.
// ---------------------------------------------------------------------------
__global__ __launch_bounds__(256) void gemm_bf16(
    const short* __restrict__ A, int lda,
    const short* __restrict__ Bt, int ldb,
    const float* __restrict__ bias,
    const float* __restrict__ bias2,
    const float* __restrict__ bias3,
    const float* __restrict__ resid,
    float* __restrict__ Cf, short* __restrict__ Cb, short* __restrict__ Cvt,
    int ldc, int K, int act, int qkv, int gx)
{
    __shared__ __align__(16) short sA[128 * 64];   // 16KB, swizzled
    __shared__ __align__(16) short sB[128 * 64];   // 16KB, swizzled
    const int tid = threadIdx.x;
    const int lane = tid & 63, wave = tid >> 6;
    const int quad = lane >> 4, l15 = lane & 15;

    // XCD row-panel swizzle (gy == 64 for all call sites: M = 8192)
    const int id = blockIdx.x;
    const int xcd = id & 7, j = id >> 3;
    const int bx = j % gx, by = xcd + 8 * (j / gx);
    const int bm = by * 128, bn = bx * 128;
    const int wm = (wave >> 1) * 64, wn = (wave & 1) * 64;

    // staging lane decomposition (invariant): row lr, swizzled chunk lc
    const int lr = lane >> 3;            // 0..7 row within an 8-row call
    const int lc = (lane & 7) ^ lr;      // chunk ^ (row&7)
    const int sw = l15 & 7;              // read-side swizzle key

    f32x4 acc[4][4];
#pragma unroll
    for (int i = 0; i < 4; i++)
#pragma unroll
        for (int jj = 0; jj < 4; jj++) acc[i][jj] = (f32x4){0.f, 0.f, 0.f, 0.f};

    for (int k0 = 0; k0 < K; k0 += 64) {
        __syncthreads();
        // stage A + B tiles: 16 calls each, 4 per wave per matrix
#pragma unroll
        for (int c = 0; c < 4; c++) {
            int cid = wave * 4 + c;                 // 0..15, rows cid*8..+7
            GLD16(A  + (size_t)(bm + cid * 8 + lr) * lda + k0 + lc * 8,
                  &sA[cid * 512]);
            GLD16(Bt + (size_t)(bn + cid * 8 + lr) * ldb + k0 + lc * 8,
                  &sB[cid * 512]);
        }
        __syncthreads();
#pragma unroll
        for (int ko = 0; ko < 2; ko++) {
            bf16x8 af[4], bfr[4];
#pragma unroll
            for (int mt = 0; mt < 4; mt++) {
                int row = wm + mt * 16 + l15;
                af[mt] = *(const bf16x8*)&sA[(row * 8 + ((ko * 4 + quad) ^ sw)) * 8];
            }
#pragma unroll
            for (int nt = 0; nt < 4; nt++) {
                int row = wn + nt * 16 + l15;
                bfr[nt] = *(const bf16x8*)&sB[(row * 8 + ((ko * 4 + quad) ^ sw)) * 8];
            }
#pragma unroll
            for (int mt = 0; mt < 4; mt++)
#pragma unroll
                for (int nt = 0; nt < 4; nt++)
                    acc[mt][nt] = MFMA16(af[mt], bfr[nt], acc[mt][nt]);
        }
    }

#pragma unroll
    for (int mt = 0; mt < 4; mt++)
#pragma unroll
        for (int nt = 0; nt < 4; nt++) {
            int row0 = bm + wm + mt * 16 + quad * 4;
            int col  = bn + wn + nt * 16 + l15;
            if (qkv) {
                int seg = col >> 10, cloc = col & 1023;
                const float* bp = (seg == 0) ? bias : (seg == 1) ? bias2 : bias3;
                float bval = bp[cloc];
                if (seg == 2) {
                    // V transposed store: page=(b*H+h)*64+d, index = seq pos
                    int bb = row0 >> 10, l0 = row0 & 1023;
                    size_t page = (size_t)(bb * N_HEAD + (cloc >> 6)) * HEAD_D + (cloc & 63);
                    short4v pk = { f2bf(acc[mt][nt][0] + bval), f2bf(acc[mt][nt][1] + bval),
                                   f2bf(acc[mt][nt][2] + bval), f2bf(acc[mt][nt][3] + bval) };
                    *(short4v*)&Cvt[page * SEQ_L + l0] = pk;
                } else {
                    short* dst = Cb + (size_t)seg * ((size_t)N_TOK * D_MODEL);
#pragma unroll
                    for (int r = 0; r < 4; r++)
                        dst[(size_t)(row0 + r) * D_MODEL + cloc] = f2bf(acc[mt][nt][r] + bval);
                }
            } else {
#pragma unroll
                for (int r = 0; r < 4; r++) {
                    int row = row0 + r;
                    float v = acc[mt][nt][r] + bias[col];
                    if (act) v = v / (1.f + __expf(-1.702f * v));   // quick_gelu
                    if (resid) v += resid[(size_t)row * ldc + col];
                    if (Cb) Cb[(size_t)row * ldc + col] = f2bf(v);
                    else    Cf[(size_t)row * ldc + col] = v;
                }
            }
        }
}

// ---------------------------------------------------------------------------
// Flash attention (unchanged from R6 — it works): bf16 MFMA, S^T form,
// K-step=128, m97-style LDS staging, log2-domain softmax, per-wave P slab.
// ---------------------------------------------------------------------------
__global__ __launch_bounds__(256) void attn_kernel(
    const short* __restrict__ Q, const short* __restrict__ Kb,
    const short* __restrict__ Vt, const float* __restrict__ fmask,
    short* __restrict__ O)
{
    __shared__ __align__(16) short sK[8192];        // 16KB: slot=kc*128+key
    __shared__ __align__(16) short sV[8192];        // 16KB: slot=kc2*64+d
    __shared__ __align__(16) short sP[4][16 * 136]; // per-wave [16 q][136]
    __shared__ __align__(16) float sAl[4][20];

    const int g = blockIdx.x;
    const int xcd = g & 7, slot = g >> 3;
    const int qt = slot & 15, bhl = slot >> 4;
    const int bh = xcd * 16 + bhl;
    const int b = bh >> 4, h = bh & 15;

    const int tid = threadIdx.x;
    const int wave = tid >> 6, lane = tid & 63;
    const int quad = lane >> 4, l15 = lane & 15;

    const int qbase = b * SEQ_L + qt * 64;
    const short* qp = Q + (size_t)(qbase + wave * 16 + l15) * D_MODEL + h * HEAD_D + quad * 8;
    bf16x8 qf0 = *(const bf16x8*)qp;
    bf16x8 qf1 = *(const bf16x8*)(qp + 32);

    const short* Kbh = Kb + (size_t)b * SEQ_L * D_MODEL + h * HEAD_D;
    const short* Vbh = Vt + (size_t)(b * N_HEAD + h) * HEAD_D * SEQ_L;
    const float* mk  = fmask + b * SEQ_L;

    f32x4 o4[4];
#pragma unroll
    for (int nt = 0; nt < 4; nt++) o4[nt] = (f32x4){0.f, 0.f, 0.f, 0.f};
    float mrow = -1e30f, lrow = 0.f;     // per-lane: q = l15 of this wave
    short* pslab = &sP[wave][0];         // per-wave private [16 q][136]
    const float CSC = 0.125f * 1.4426950408889634f;   // scale * log2(e)

    for (int kt = 0; kt < SEQ_L / 128; kt++) {
        __syncthreads();   // previous iter's frag reads done
        // ---- stage K-tile + V^T-tile (8 GLD16 per wave, no VGPR data) ----
#pragma unroll
        for (int j = 0; j < 4; j++) {
            int cid = wave * 4 + j;
            int kc = cid >> 1, key0 = (cid & 1) << 6;
            GLD16(Kbh + (size_t)(kt * 128 + key0 + lane) * D_MODEL + kc * 8,
                  &sK[cid * 512]);
            GLD16(Vbh + (size_t)lane * SEQ_L + kt * 128 + cid * 8,
                  &sV[cid * 512]);
        }
        __syncthreads();   // staging complete (vmcnt drained by barrier)

        // ---- mask loads (f32x4, indexed by key=row) ----
        f32x4 mkv[8];
#pragma unroll
        for (int sub = 0; sub < 8; sub++)
            mkv[sub] = *(const f32x4*)&mk[kt * 128 + sub * 16 + quad * 4];

        // ---- S^T = K·Q^T : D[m=key][n=q] ----
        f32x4 s[8];
#pragma unroll
        for (int sub = 0; sub < 8; sub++) {
            bf16x8 kf0 = *(const bf16x8*)&sK[(quad * 128 + sub * 16 + l15) * 8];
            bf16x8 kf1 = *(const bf16x8*)&sK[((quad + 4) * 128 + sub * 16 + l15) * 8];
            s[sub] = (f32x4){0.f, 0.f, 0.f, 0.f};
            s[sub] = MFMA16(kf0, qf0, s[sub]);
            s[sub] = MFMA16(kf1, qf1, s[sub]);
        }
        // ---- scale+mask in one FMA (log2 domain) ----
#pragma unroll
        for (int sub = 0; sub < 8; sub++)
#pragma unroll
            for (int r = 0; r < 4; r++) s[sub][r] = s[sub][r] * CSC + mkv[sub][r];

        // ---- per-lane max over 32 scores + 2 shuffles ----
        f32x4 mx4 = s[0];
#pragma unroll
        for (int sub = 1; sub < 8; sub++)
#pragma unroll
            for (int r = 0; r < 4; r++) mx4[r] = fmaxf(mx4[r], s[sub][r]);
        float pmax = fmaxf(fmaxf(mx4[0], mx4[1]), fmaxf(mx4[2], mx4[3]));
        pmax = fmaxf(pmax, __shfl_xor(pmax, 16));
        pmax = fmaxf(pmax, __shfl_xor(pmax, 32));
        float mnew = fmaxf(mrow, pmax);
        float alpha = EXP2F(mrow - mnew);
        mrow = mnew;
        if (quad == 0) sAl[wave][l15] = alpha;   // broadcast to O rows

        // ---- exp2 + pairwise pack + P writes ----
        float ls = 0.f;
#pragma unroll
        for (int sub = 0; sub < 8; sub++) {
            float p0 = EXP2F(s[sub][0] - mnew);
            float p1 = EXP2F(s[sub][1] - mnew);
            float p2 = EXP2F(s[sub][2] - mnew);
            float p3 = EXP2F(s[sub][3] - mnew);
            ls += (p0 + p1) + (p2 + p3);
            int2v pk = { pack2bf(p0, p1), pack2bf(p2, p3) };
            *(int2v*)&pslab[l15 * 136 + sub * 16 + quad * 4] = pk;
        }
        ls += __shfl_xor(ls, 16);
        ls += __shfl_xor(ls, 32);
        lrow = lrow * alpha + ls;

        // ---- rescale O by alpha (read per-row broadcast) ----
        f32x4 av = *(const f32x4*)&sAl[wave][quad * 4];
#pragma unroll
        for (int nt = 0; nt < 4; nt++)
#pragma unroll
            for (int r = 0; r < 4; r++) o4[nt][r] *= av[r];

        // ---- PV: P A-frags from slab, V B-frags from sV ----
        bf16x8 pf[4];
#pragma unroll
        for (int c = 0; c < 4; c++)
            pf[c] = *(const bf16x8*)&pslab[l15 * 136 + c * 32 + quad * 8];
#pragma unroll
        for (int nt = 0; nt < 4; nt++)
#pragma unroll
            for (int c = 0; c < 4; c++) {
                bf16x8 vfr = *(const bf16x8*)&sV[((c * 4 + quad) * 64 + nt * 16 + l15) * 8];
                o4[nt] = MFMA16(pf[c], vfr, o4[nt]);
            }
    }
    // final 1/l broadcast to O rows
    if (quad == 0) sAl[wave][l15] = 1.f / lrow;
    __syncthreads();
    f32x4 iv = *(const f32x4*)&sAl[wave][quad * 4];
#pragma unroll
    for (int nt = 0; nt < 4; nt++)
#pragma unroll
        for (int r = 0; r < 4; r++)
            O[(size_t)(qbase + wave * 16 + quad * 4 + r) * D_MODEL
              + h * HEAD_D + nt * 16 + l15] = f2bf(o4[nt][r] * iv[r]);
}

// ---------------------------------------------------------------------------
// Launch
// ---------------------------------------------------------------------------
extern "C" void kernel_launch(void* const* d_in, const int* in_sizes, int n_in,
                              void* d_out, int out_size, void* d_ws, size_t ws_size,
                              hipStream_t stream)
{
    const float* x     = (const float*)d_in[0];
    const int*   amask = (const int*)  d_in[1];
    const float* wq    = (const float*)d_in[2];
    const float* bq    = (const float*)d_in[3];
    const float* wk    = (const float*)d_in[4];
    const float* bk    = (const float*)d_in[5];
    const float* wv    = (const float*)d_in[6];
    const float* bv    = (const float*)d_in[7];
    const float* wo    = (const float*)d_in[8];
    const float* bo    = (const float*)d_in[9];
    const float* ln1s  = (const float*)d_in[10];
    const float* ln1b  = (const float*)d_in[11];
    const float* ln2s  = (const float*)d_in[12];
    const float* ln2b  = (const float*)d_in[13];
    const float* w1    = (const float*)d_in[14];
    const float* b1    = (const float*)d_in[15];
    const float* w2    = (const float*)d_in[16];
    const float* b2    = (const float*)d_in[17];
    float* out = (float*)d_out;

    // workspace layout (bytes; peak 104 MB, proven available)
    char* w = (char*)d_ws;
    short* wqkvt = (short*)(w + (size_t)0);          // [3072][1024] bf16, 6MB
    short* wot   = (short*)(w + ((size_t)6  << 20));
    short* w1t   = (short*)(w + ((size_t)8  << 20));
    short* w2t   = (short*)(w + ((size_t)16 << 20));
    short* hb    = (short*)(w + ((size_t)24 << 20)); // LN1 out, later LN2 out
    short* qb    = (short*)(w + ((size_t)40 << 20)); // qb,kbf contiguous:
    short* kbf   = (short*)(w + ((size_t)56 << 20)); //   16MB stride for qkv mode
    short* attnb = (short*)(w + ((size_t)72 << 20));
    short* vtb   = (short*)(w + ((size_t)88 << 20));
    short* ffb   = qb;   // q/k/vt dead by MLP1 (64 MB span 40..104)
    // fmask lives in d_out: free until the O-proj GEMM (step 4) overwrites
    // it, and attn (step 3) has finished reading it by then (same stream).
    // R8 BUG: fmask aliased hb and LN1 clobbered it -> absmax 0.39.
    float* fmaskb = (float*)d_out;

    dim3 blk(256);

    // prep: six transposes + mask in ONE dispatch
    prep_kernel<<<dim3(12320), blk, 0, stream>>>(wq, wk, wv, wo, w1, w2, amask,
                                                 wqkvt, wot, w1t, w2t, fmaskb);

    // 1) h = LN1(x) -> bf16
    ln_kernel<<<N_TOK, blk, 0, stream>>>(x, ln1s, ln1b, hb);

    // 2) fused QKV GEMM (gx=24): writes qb, kbf, V transposed (vtb)
    gemm_bf16<<<dim3(24 * 64), blk, 0, stream>>>(
        hb, 1024, wqkvt, 1024, bq, bk, bv, nullptr,
        nullptr, qb, vtb, 1024, 1024, 0, 1, 24);

    // 3) flash attention -> attnb (bf16); 1-D grid, XCD swizzle inside
    attn_kernel<<<dim3(2048), blk, 0, stream>>>(qb, kbf, vtb, fmaskb, attnb);

    // 4) out = x + attn @ wo + bo  (fp32 out, gx=8) — overwrites fmask region
    gemm_bf16<<<dim3(8 * 64), blk, 0, stream>>>(
        attnb, 1024, wot, 1024, bo, nullptr, nullptr, x,
        out, nullptr, nullptr, 1024, 1024, 0, 0, 8);

    // 5) h = LN2(out) -> bf16
    ln_kernel<<<N_TOK, blk, 0, stream>>>(out, ln2s, ln2b, hb);

    // 6) MLP (gx=32, then gx=8)
    gemm_bf16<<<dim3(32 * 64), blk, 0, stream>>>(
        hb, 1024, w1t, 1024, b1, nullptr, nullptr, nullptr,
        nullptr, ffb, nullptr, 4096, 1024, 1, 0, 32);
    gemm_bf16<<<dim3(8 * 64), blk, 0, stream>>>(
        ffb, 4096, w2t, 4096, b2, nullptr, nullptr, out,
        out, nullptr, nullptr, 1024, 4096, 0, 0, 8);
}

// Round 10
// 574.353 us; speedup vs baseline: 1.3064x; 1.0251x over previous
//
#include <hip/hip_runtime.h>
#include <math.h>

#define D_MODEL 1024
#define N_TOK   8192
#define SEQ_L   1024
#define N_HEAD  16
#define HEAD_D  64
#define FF_DIM  4096

typedef __attribute__((ext_vector_type(8))) short bf16x8;   // 8 bf16 = 4 VGPRs
typedef __attribute__((ext_vector_type(4))) short short4v;
typedef __attribute__((ext_vector_type(2))) int  int2v;
typedef __attribute__((ext_vector_type(4))) float f32x4;

#define MFMA16(a, b, c) __builtin_amdgcn_mfma_f32_16x16x32_bf16((a), (b), (c), 0, 0, 0)

// async global->LDS, 16B per lane; LDS dest = wave-uniform base + lane*16
#define GLD16(gp, lp) __builtin_amdgcn_global_load_lds(                      \
    (const __attribute__((address_space(1))) void*)(gp),                     \
    (__attribute__((address_space(3))) void*)(lp), 16, 0, 0)

#if defined(__has_builtin)
#if __has_builtin(__builtin_amdgcn_exp2f)
#define EXP2F(x) __builtin_amdgcn_exp2f(x)
#else
#define EXP2F(x) exp2f(x)
#endif
#else
#define EXP2F(x) exp2f(x)
#endif

__device__ __forceinline__ short f2bf(float f) {   // fp32 -> bf16 (RNE)
    unsigned u = __float_as_uint(f);
    u += 0x7fffu + ((u >> 16) & 1u);
    return (short)(u >> 16);
}

// pack two fp32 -> two bf16 (round-nearest-up) in one v_perm
__device__ __forceinline__ int pack2bf(float a, float b) {
    unsigned ua = __float_as_uint(a) + 0x8000u;
    unsigned ub = __float_as_uint(b) + 0x8000u;
    return __builtin_amdgcn_perm(ub, ua, 0x07060302u);
}

// ---------------------------------------------------------------------------
// LayerNorm fp32 -> bf16. One block (256 thr) per token.
// ---------------------------------------------------------------------------
__global__ __launch_bounds__(256) void ln_kernel(const float* __restrict__ x,
                                                 const float* __restrict__ g,
                                                 const float* __restrict__ b,
                                                 short* __restrict__ o)
{
    int t = blockIdx.x;
    const float* xr = x + (size_t)t * D_MODEL;
    short* orow = o + (size_t)t * D_MODEL;
    float vals[4];
    float lsum = 0.f, lsq = 0.f;
#pragma unroll
    for (int i = 0; i < 4; i++) {
        float v = xr[threadIdx.x + i * 256];
        vals[i] = v; lsum += v; lsq += v * v;
    }
#pragma unroll
    for (int off = 32; off > 0; off >>= 1) {
        lsum += __shfl_down(lsum, off);
        lsq  += __shfl_down(lsq,  off);
    }
    __shared__ float red[8];
    int wid = threadIdx.x >> 6, lane = threadIdx.x & 63;
    if (lane == 0) { red[wid] = lsum; red[4 + wid] = lsq; }
    __syncthreads();
    if (threadIdx.x == 0) {
        red[0] = red[0] + red[1] + red[2] + red[3];
        red[4] = red[4] + red[5] + red[6] + red[7];
    }
    __syncthreads();
    float mean = red[0] * (1.f / D_MODEL);
    float var  = red[4] * (1.f / D_MODEL) - mean * mean;
    float inv  = rsqrtf(var + 1e-5f);
#pragma unroll
    for (int i = 0; i < 4; i++) {
        int c = threadIdx.x + i * 256;
        orow[c] = f2bf((vals[i] - mean) * inv * g[c] + b[c]);
    }
}

// ---------------------------------------------------------------------------
// Fused prep: six W [K,N] fp32 -> W^T [N,K] bf16 transposes + fp32 mask,
// all in ONE dispatch. Block id ranges select the job; 32x32 tiles.
// fmask target lives in d_out (free until the O-proj GEMM writes it).
// ---------------------------------------------------------------------------
__global__ __launch_bounds__(256) void prep_kernel(
    const float* __restrict__ wq, const float* __restrict__ wk,
    const float* __restrict__ wv, const float* __restrict__ wo,
    const float* __restrict__ w1, const float* __restrict__ w2,
    const int*   __restrict__ amask,
    short* __restrict__ wqkvt, short* __restrict__ wot,
    short* __restrict__ w1t,  short* __restrict__ w2t,
    float* __restrict__ fmask)
{
    int id = blockIdx.x;
    if (id >= 12288) {   // mask job: 32 blocks x 256 = 8192 entries
        int i = (id - 12288) * 256 + threadIdx.x;
        fmask[i] = (amask[i] > 0) ? 0.f : -1e30f;
        return;
    }
    const float* src; short* dst; int R, C, tloc, csh;
    if (id < 4096) {
        int wsel = id >> 10; tloc = id & 1023; R = 1024; C = 1024; csh = 5;
        src = (wsel == 0) ? wq : (wsel == 1) ? wk : (wsel == 2) ? wv : wo;
        dst = (wsel == 3) ? wot : (wqkvt + (size_t)wsel * 1024 * 1024);
    } else if (id < 8192) {
        tloc = id - 4096; R = 1024; C = 4096; csh = 7; src = w1; dst = w1t;
    } else {
        tloc = id - 8192; R = 4096; C = 1024; csh = 5; src = w2; dst = w2t;
    }
    int ty = tloc >> csh, tx = tloc & ((1 << csh) - 1);
    int r0 = ty * 32, c0 = tx * 32;
    __shared__ float t[32][33];
    int tid = threadIdx.x;
#pragma unroll
    for (int i = 0; i < 4; i++) {
        int idx = i * 256 + tid;
        int r = idx >> 5, c = idx & 31;
        t[r][c] = src[(size_t)(r0 + r) * C + c0 + c];
    }
    __syncthreads();
#pragma unroll
    for (int i = 0; i < 4; i++) {
        int idx = i * 256 + tid;
        int rr = idx >> 5, cc = idx & 31;
        dst[(size_t)(c0 + rr) * R + r0 + cc] = f2bf(t[cc][rr]);
    }
}

// ---------------------------------------------------------------------------
// bf16 MFMA GEMM, BK=64, XOR-swizzled LDS, DOUBLE-BUFFERED prefetch:
//   barrier -> stage(k+1, other buf) -> compute(k)  so GLD16 latency for
//   k+1 overlaps 32 MFMAs + 16 ds_reads of k; the next barrier's vmcnt(0)
//   drain pays only the residual. Barrier at iter k+1 also proves all
//   reads of buf[k&1] finished (lgkm drained) before iter k+2 overwrites.
// LDS slot(row, chunk) = row*8 + (chunk ^ (row&7))  [16B slots]:
//   staging keeps 128B-segment coalescing, frag reads conflict-free.
// Grid: 1-D, XCD row-panel swizzle (gy==64): xcd=id&7 owns rows {xcd+8j}.
// C/D layout: col=lane&15, row=quad*4+reg.
// Modes: qkv=1 (fused QKV, V transposed store) / bias+gelu+resid, f32/bf16.
// ---------------------------------------------------------------------------
__global__ __launch_bounds__(256) void gemm_bf16(
    const short* __restrict__ A, int lda,
    const short* __restrict__ Bt, int ldb,
    const float* __restrict__ bias,
    const float* __restrict__ bias2,
    const float* __restrict__ bias3,
    const float* __restrict__ resid,
    float* __restrict__ Cf, short* __restrict__ Cb, short* __restrict__ Cvt,
    int ldc, int K, int act, int qkv, int gx)
{
    __shared__ __align__(16) short sA[2][128 * 64];   // 2 x 16KB, swizzled
    __shared__ __align__(16) short sB[2][128 * 64];
    const int tid = threadIdx.x;
    const int lane = tid & 63, wave = tid >> 6;
    const int quad = lane >> 4, l15 = lane & 15;

    // XCD row-panel swizzle (gy == 64 for all call sites: M = 8192)
    const int id = blockIdx.x;
    const int xcd = id & 7, j = id >> 3;
    const int bx = j % gx, by = xcd + 8 * (j / gx);
    const int bm = by * 128, bn = bx * 128;
    const int wm = (wave >> 1) * 64, wn = (wave & 1) * 64;

    // staging lane decomposition (invariant): row lr, swizzled chunk lc
    const int lr = lane >> 3;            // 0..7 row within an 8-row call
    const int lc = (lane & 7) ^ lr;      // chunk ^ (row&7)
    const int sw = l15 & 7;              // read-side swizzle key

    // global row bases for this thread's 4 staging calls (cid = wave*4+c)
    const short* Ab = A  + (size_t)(bm + wave * 32 + lr) * lda + lc * 8;
    const short* Bb = Bt + (size_t)(bn + wave * 32 + lr) * ldb + lc * 8;

    f32x4 acc[4][4];
#pragma unroll
    for (int i = 0; i < 4; i++)
#pragma unroll
        for (int jj = 0; jj < 4; jj++) acc[i][jj] = (f32x4){0.f, 0.f, 0.f, 0.f};

    const int nk = K >> 6;
    // prologue: stage tile 0 into buf 0
#pragma unroll
    for (int c = 0; c < 4; c++) {
        int cid = wave * 4 + c;
        GLD16(Ab + (size_t)(c * 8) * lda, &sA[0][cid * 512]);
        GLD16(Bb + (size_t)(c * 8) * ldb, &sB[0][cid * 512]);
    }

    for (int ki = 0; ki < nk; ki++) {
        __syncthreads();   // staging of buf[ki&1] visible; reads of buf[ki&1 ^ 1] done
        if (ki + 1 < nk) {
            int k0 = (ki + 1) << 6, nb = (ki + 1) & 1;
#pragma unroll
            for (int c = 0; c < 4; c++) {
                int cid = wave * 4 + c;
                GLD16(Ab + (size_t)(c * 8) * lda + k0, &sA[nb][cid * 512]);
                GLD16(Bb + (size_t)(c * 8) * ldb + k0, &sB[nb][cid * 512]);
            }
        }
        const short* cA = sA[ki & 1];
        const short* cB = sB[ki & 1];
#pragma unroll
        for (int ko = 0; ko < 2; ko++) {
            bf16x8 af[4], bfr[4];
#pragma unroll
            for (int mt = 0; mt < 4; mt++) {
                int row = wm + mt * 16 + l15;
                af[mt] = *(const bf16x8*)&cA[(row * 8 + ((ko * 4 + quad) ^ sw)) * 8];
            }
#pragma unroll
            for (int nt = 0; nt < 4; nt++) {
                int row = wn + nt * 16 + l15;
                bfr[nt] = *(const bf16x8*)&cB[(row * 8 + ((ko * 4 + quad) ^ sw)) * 8];
            }
#pragma unroll
            for (int mt = 0; mt < 4; mt++)
#pragma unroll
                for (int nt = 0; nt < 4; nt++)
                    acc[mt][nt] = MFMA16(af[mt], bfr[nt], acc[mt][nt]);
        }
    }

#pragma unroll
    for (int mt = 0; mt < 4; mt++)
#pragma unroll
        for (int nt = 0; nt < 4; nt++) {
            int row0 = bm + wm + mt * 16 + quad * 4;
            int col  = bn + wn + nt * 16 + l15;
            if (qkv) {
                int seg = col >> 10, cloc = col & 1023;
                const float* bp = (seg == 0) ? bias : (seg == 1) ? bias2 : bias3;
                float bval = bp[cloc];
                if (seg == 2) {
                    // V transposed store: page=(b*H+h)*64+d, index = seq pos
                    int bb = row0 >> 10, l0 = row0 & 1023;
                    size_t page = (size_t)(bb * N_HEAD + (cloc >> 6)) * HEAD_D + (cloc & 63);
                    short4v pk = { f2bf(acc[mt][nt][0] + bval), f2bf(acc[mt][nt][1] + bval),
                                   f2bf(acc[mt][nt][2] + bval), f2bf(acc[mt][nt][3] + bval) };
                    *(short4v*)&Cvt[page * SEQ_L + l0] = pk;
                } else {
                    short* dst = Cb + (size_t)seg * ((size_t)N_TOK * D_MODEL);
#pragma unroll
                    for (int r = 0; r < 4; r++)
                        dst[(size_t)(row0 + r) * D_MODEL + cloc] = f2bf(acc[mt][nt][r] + bval);
                }
            } else {
#pragma unroll
                for (int r = 0; r < 4; r++) {
                    int row = row0 + r;
                    float v = acc[mt][nt][r] + bias[col];
                    if (act) v = v / (1.f + __expf(-1.702f * v));   // quick_gelu
                    if (resid) v += resid[(size_t)row * ldc + col];
                    if (Cb) Cb[(size_t)row * ldc + col] = f2bf(v);
                    else    Cf[(size_t)row * ldc + col] = v;
                }
            }
        }
}

// ---------------------------------------------------------------------------
// Flash attention (unchanged from R6 — it works): bf16 MFMA, S^T form,
// K-step=128, m97-style LDS staging, log2-domain softmax, per-wave P slab.
// ---------------------------------------------------------------------------
__global__ __launch_bounds__(256) void attn_kernel(
    const short* __restrict__ Q, const short* __restrict__ Kb,
    const short* __restrict__ Vt, const float* __restrict__ fmask,
    short* __restrict__ O)
{
    __shared__ __align__(16) short sK[8192];        // 16KB: slot=kc*128+key
    __shared__ __align__(16) short sV[8192];        // 16KB: slot=kc2*64+d
    __shared__ __align__(16) short sP[4][16 * 136]; // per-wave [16 q][136]
    __shared__ __align__(16) float sAl[4][20];

    const int g = blockIdx.x;
    const int xcd = g & 7, slot = g >> 3;
    const int qt = slot & 15, bhl = slot >> 4;
    const int bh = xcd * 16 + bhl;
    const int b = bh >> 4, h = bh & 15;

    const int tid = threadIdx.x;
    const int wave = tid >> 6, lane = tid & 63;
    const int quad = lane >> 4, l15 = lane & 15;

    const int qbase = b * SEQ_L + qt * 64;
    const short* qp = Q + (size_t)(qbase + wave * 16 + l15) * D_MODEL + h * HEAD_D + quad * 8;
    bf16x8 qf0 = *(const bf16x8*)qp;
    bf16x8 qf1 = *(const bf16x8*)(qp + 32);

    const short* Kbh = Kb + (size_t)b * SEQ_L * D_MODEL + h * HEAD_D;
    const short* Vbh = Vt + (size_t)(b * N_HEAD + h) * HEAD_D * SEQ_L;
    const float* mk  = fmask + b * SEQ_L;

    f32x4 o4[4];
#pragma unroll
    for (int nt = 0; nt < 4; nt++) o4[nt] = (f32x4){0.f, 0.f, 0.f, 0.f};
    float mrow = -1e30f, lrow = 0.f;     // per-lane: q = l15 of this wave
    short* pslab = &sP[wave][0];         // per-wave private [16 q][136]
    const float CSC = 0.125f * 1.4426950408889634f;   // scale * log2(e)

    for (int kt = 0; kt < SEQ_L / 128; kt++) {
        __syncthreads();   // previous iter's frag reads done
        // ---- stage K-tile + V^T-tile (8 GLD16 per wave, no VGPR data) ----
#pragma unroll
        for (int j = 0; j < 4; j++) {
            int cid = wave * 4 + j;
            int kc = cid >> 1, key0 = (cid & 1) << 6;
            GLD16(Kbh + (size_t)(kt * 128 + key0 + lane) * D_MODEL + kc * 8,
                  &sK[cid * 512]);
            GLD16(Vbh + (size_t)lane * SEQ_L + kt * 128 + cid * 8,
                  &sV[cid * 512]);
        }
        __syncthreads();   // staging complete (vmcnt drained by barrier)

        // ---- mask loads (f32x4, indexed by key=row) ----
        f32x4 mkv[8];
#pragma unroll
        for (int sub = 0; sub < 8; sub++)
            mkv[sub] = *(const f32x4*)&mk[kt * 128 + sub * 16 + quad * 4];

        // ---- S^T = K·Q^T : D[m=key][n=q] ----
        f32x4 s[8];
#pragma unroll
        for (int sub = 0; sub < 8; sub++) {
            bf16x8 kf0 = *(const bf16x8*)&sK[(quad * 128 + sub * 16 + l15) * 8];
            bf16x8 kf1 = *(const bf16x8*)&sK[((quad + 4) * 128 + sub * 16 + l15) * 8];
            s[sub] = (f32x4){0.f, 0.f, 0.f, 0.f};
            s[sub] = MFMA16(kf0, qf0, s[sub]);
            s[sub] = MFMA16(kf1, qf1, s[sub]);
        }
        // ---- scale+mask in one FMA (log2 domain) ----
#pragma unroll
        for (int sub = 0; sub < 8; sub++)
#pragma unroll
            for (int r = 0; r < 4; r++) s[sub][r] = s[sub][r] * CSC + mkv[sub][r];

        // ---- per-lane max over 32 scores + 2 shuffles ----
        f32x4 mx4 = s[0];
#pragma unroll
        for (int sub = 1; sub < 8; sub++)
#pragma unroll
            for (int r = 0; r < 4; r++) mx4[r] = fmaxf(mx4[r], s[sub][r]);
        float pmax = fmaxf(fmaxf(mx4[0], mx4[1]), fmaxf(mx4[2], mx4[3]));
        pmax = fmaxf(pmax, __shfl_xor(pmax, 16));
        pmax = fmaxf(pmax, __shfl_xor(pmax, 32));
        float mnew = fmaxf(mrow, pmax);
        float alpha = EXP2F(mrow - mnew);
        mrow = mnew;
        if (quad == 0) sAl[wave][l15] = alpha;   // broadcast to O rows

        // ---- exp2 + pairwise pack + P writes ----
        float ls = 0.f;
#pragma unroll
        for (int sub = 0; sub < 8; sub++) {
            float p0 = EXP2F(s[sub][0] - mnew);
            float p1 = EXP2F(s[sub][1] - mnew);
            float p2 = EXP2F(s[sub][2] - mnew);
            float p3 = EXP2F(s[sub][3] - mnew);
            ls += (p0 + p1) + (p2 + p3);
            int2v pk = { pack2bf(p0, p1), pack2bf(p2, p3) };
            *(int2v*)&pslab[l15 * 136 + sub * 16 + quad * 4] = pk;
        }
        ls += __shfl_xor(ls, 16);
        ls += __shfl_xor(ls, 32);
        lrow = lrow * alpha + ls;

        // ---- rescale O by alpha (read per-row broadcast) ----
        f32x4 av = *(const f32x4*)&sAl[wave][quad * 4];
#pragma unroll
        for (int nt = 0; nt < 4; nt++)
#pragma unroll
            for (int r = 0; r < 4; r++) o4[nt][r] *= av[r];

        // ---- PV: P A-frags from slab, V B-frags from sV ----
        bf16x8 pf[4];
#pragma unroll
        for (int c = 0; c < 4; c++)
            pf[c] = *(const bf16x8*)&pslab[l15 * 136 + c * 32 + quad * 8];
#pragma unroll
        for (int nt = 0; nt < 4; nt++)
#pragma unroll
            for (int c = 0; c < 4; c++) {
                bf16x8 vfr = *(const bf16x8*)&sV[((c * 4 + quad) * 64 + nt * 16 + l15) * 8];
                o4[nt] = MFMA16(pf[c], vfr, o4[nt]);
            }
    }
    // final 1/l broadcast to O rows
    if (quad == 0) sAl[wave][l15] = 1.f / lrow;
    __syncthreads();
    f32x4 iv = *(const f32x4*)&sAl[wave][quad * 4];
#pragma unroll
    for (int nt = 0; nt < 4; nt++)
#pragma unroll
        for (int r = 0; r < 4; r++)
            O[(size_t)(qbase + wave * 16 + quad * 4 + r) * D_MODEL
              + h * HEAD_D + nt * 16 + l15] = f2bf(o4[nt][r] * iv[r]);
}

// ---------------------------------------------------------------------------
// Launch
// ---------------------------------------------------------------------------
extern "C" void kernel_launch(void* const* d_in, const int* in_sizes, int n_in,
                              void* d_out, int out_size, void* d_ws, size_t ws_size,
                              hipStream_t stream)
{
    const float* x     = (const float*)d_in[0];
    const int*   amask = (const int*)  d_in[1];
    const float* wq    = (const float*)d_in[2];
    const float* bq    = (const float*)d_in[3];
    const float* wk    = (const float*)d_in[4];
    const float* bk    = (const float*)d_in[5];
    const float* wv    = (const float*)d_in[6];
    const float* bv    = (const float*)d_in[7];
    const float* wo    = (const float*)d_in[8];
    const float* bo    = (const float*)d_in[9];
    const float* ln1s  = (const float*)d_in[10];
    const float* ln1b  = (const float*)d_in[11];
    const float* ln2s  = (const float*)d_in[12];
    const float* ln2b  = (const float*)d_in[13];
    const float* w1    = (const float*)d_in[14];
    const float* b1    = (const float*)d_in[15];
    const float* w2    = (const float*)d_in[16];
    const float* b2    = (const float*)d_in[17];
    float* out = (float*)d_out;

    // workspace layout (bytes; peak 104 MB, proven available)
    char* w = (char*)d_ws;
    short* wqkvt = (short*)(w + (size_t)0);          // [3072][1024] bf16, 6MB
    short* wot   = (short*)(w + ((size_t)6  << 20));
    short* w1t   = (short*)(w + ((size_t)8  << 20));
    short* w2t   = (short*)(w + ((size_t)16 << 20));
    short* hb    = (short*)(w + ((size_t)24 << 20)); // LN1 out, later LN2 out
    short* qb    = (short*)(w + ((size_t)40 << 20)); // qb,kbf contiguous:
    short* kbf   = (short*)(w + ((size_t)56 << 20)); //   16MB stride for qkv mode
    short* attnb = (short*)(w + ((size_t)72 << 20));
    short* vtb   = (short*)(w + ((size_t)88 << 20));
    short* ffb   = qb;   // q/k/vt dead by MLP1 (64 MB span 40..104)
    // fmask lives in d_out: free until the O-proj GEMM (step 4) overwrites
    // it, and attn (step 3) has finished reading it by then (same stream).
    float* fmaskb = (float*)d_out;

    dim3 blk(256);

    // prep: six transposes + mask in ONE dispatch
    prep_kernel<<<dim3(12320), blk, 0, stream>>>(wq, wk, wv, wo, w1, w2, amask,
                                                 wqkvt, wot, w1t, w2t, fmaskb);

    // 1) h = LN1(x) -> bf16
    ln_kernel<<<N_TOK, blk, 0, stream>>>(x, ln1s, ln1b, hb);

    // 2) fused QKV GEMM (gx=24): writes qb, kbf, V transposed (vtb)
    gemm_bf16<<<dim3(24 * 64), blk, 0, stream>>>(
        hb, 1024, wqkvt, 1024, bq, bk, bv, nullptr,
        nullptr, qb, vtb, 1024, 1024, 0, 1, 24);

    // 3) flash attention -> attnb (bf16); 1-D grid, XCD swizzle inside
    attn_kernel<<<dim3(2048), blk, 0, stream>>>(qb, kbf, vtb, fmaskb, attnb);

    // 4) out = x + attn @ wo + bo  (fp32 out, gx=8) — overwrites fmask region
    gemm_bf16<<<dim3(8 * 64), blk, 0, stream>>>(
        attnb, 1024, wot, 1024, bo, nullptr, nullptr, x,
        out, nullptr, nullptr, 1024, 1024, 0, 0, 8);

    // 5) h = LN2(out) -> bf16
    ln_kernel<<<N_TOK, blk, 0, stream>>>(out, ln2s, ln2b, hb);

    // 6) MLP (gx=32, then gx=8)
    gemm_bf16<<<dim3(32 * 64), blk, 0, stream>>>(
        hb, 1024, w1t, 1024, b1, nullptr, nullptr, nullptr,
        nullptr, ffb, nullptr, 4096, 1024, 1, 0, 32);
    gemm_bf16<<<dim3(8 * 64), blk, 0, stream>>>(
        ffb, 4096, w2t, 4096, b2, nullptr, nullptr, out,
        out, nullptr, nullptr, 1024, 4096, 0, 0, 8);
}

// Round 11
// 554.846 us; speedup vs baseline: 1.3523x; 1.0352x over previous
//
#include <hip/hip_runtime.h>
#include <math.h>

#define D_MODEL 1024
#define N_TOK   8192
#define SEQ_L   1024
#define N_HEAD  16
#define HEAD_D  64
#define FF_DIM  4096

typedef __attribute__((ext_vector_type(8))) short bf16x8;   // 8 bf16 = 4 VGPRs
typedef __attribute__((ext_vector_type(4))) short short4v;
typedef __attribute__((ext_vector_type(2))) int  int2v;
typedef __attribute__((ext_vector_type(4))) float f32x4;

#define MFMA16(a, b, c) __builtin_amdgcn_mfma_f32_16x16x32_bf16((a), (b), (c), 0, 0, 0)

// async global->LDS, 16B per lane; LDS dest = wave-uniform base + lane*16
#define GLD16(gp, lp) __builtin_amdgcn_global_load_lds(                      \
    (const __attribute__((address_space(1))) void*)(gp),                     \
    (__attribute__((address_space(3))) void*)(lp), 16, 0, 0)

#if defined(__has_builtin)
#if __has_builtin(__builtin_amdgcn_exp2f)
#define EXP2F(x) __builtin_amdgcn_exp2f(x)
#else
#define EXP2F(x) exp2f(x)
#endif
#else
#define EXP2F(x) exp2f(x)
#endif

__device__ __forceinline__ short f2bf(float f) {   // fp32 -> bf16 (RNE)
    unsigned u = __float_as_uint(f);
    u += 0x7fffu + ((u >> 16) & 1u);
    return (short)(u >> 16);
}

// pack two fp32 -> two bf16 (round-nearest-up) in one v_perm
__device__ __forceinline__ int pack2bf(float a, float b) {
    unsigned ua = __float_as_uint(a) + 0x8000u;
    unsigned ub = __float_as_uint(b) + 0x8000u;
    return __builtin_amdgcn_perm(ub, ua, 0x07060302u);
}

// ---------------------------------------------------------------------------
// LayerNorm fp32 -> bf16. One block (256 thr) per token.
// ---------------------------------------------------------------------------
__global__ __launch_bounds__(256) void ln_kernel(const float* __restrict__ x,
                                                 const float* __restrict__ g,
                                                 const float* __restrict__ b,
                                                 short* __restrict__ o)
{
    int t = blockIdx.x;
    const float* xr = x + (size_t)t * D_MODEL;
    short* orow = o + (size_t)t * D_MODEL;
    float vals[4];
    float lsum = 0.f, lsq = 0.f;
#pragma unroll
    for (int i = 0; i < 4; i++) {
        float v = xr[threadIdx.x + i * 256];
        vals[i] = v; lsum += v; lsq += v * v;
    }
#pragma unroll
    for (int off = 32; off > 0; off >>= 1) {
        lsum += __shfl_down(lsum, off);
        lsq  += __shfl_down(lsq,  off);
    }
    __shared__ float red[8];
    int wid = threadIdx.x >> 6, lane = threadIdx.x & 63;
    if (lane == 0) { red[wid] = lsum; red[4 + wid] = lsq; }
    __syncthreads();
    if (threadIdx.x == 0) {
        red[0] = red[0] + red[1] + red[2] + red[3];
        red[4] = red[4] + red[5] + red[6] + red[7];
    }
    __syncthreads();
    float mean = red[0] * (1.f / D_MODEL);
    float var  = red[4] * (1.f / D_MODEL) - mean * mean;
    float inv  = rsqrtf(var + 1e-5f);
#pragma unroll
    for (int i = 0; i < 4; i++) {
        int c = threadIdx.x + i * 256;
        orow[c] = f2bf((vals[i] - mean) * inv * g[c] + b[c]);
    }
}

// ---------------------------------------------------------------------------
// Fused prep: six W [K,N] fp32 -> W^T [N,K] bf16 transposes + fp32 mask,
// all in ONE dispatch. Block id ranges select the job; 32x32 tiles.
// fmask target lives in d_out (free until the O-proj GEMM writes it).
// ---------------------------------------------------------------------------
__global__ __launch_bounds__(256) void prep_kernel(
    const float* __restrict__ wq, const float* __restrict__ wk,
    const float* __restrict__ wv, const float* __restrict__ wo,
    const float* __restrict__ w1, const float* __restrict__ w2,
    const int*   __restrict__ amask,
    short* __restrict__ wqkvt, short* __restrict__ wot,
    short* __restrict__ w1t,  short* __restrict__ w2t,
    float* __restrict__ fmask)
{
    int id = blockIdx.x;
    if (id >= 12288) {   // mask job: 32 blocks x 256 = 8192 entries
        int i = (id - 12288) * 256 + threadIdx.x;
        fmask[i] = (amask[i] > 0) ? 0.f : -1e30f;
        return;
    }
    const float* src; short* dst; int R, C, tloc, csh;
    if (id < 4096) {
        int wsel = id >> 10; tloc = id & 1023; R = 1024; C = 1024; csh = 5;
        src = (wsel == 0) ? wq : (wsel == 1) ? wk : (wsel == 2) ? wv : wo;
        dst = (wsel == 3) ? wot : (wqkvt + (size_t)wsel * 1024 * 1024);
    } else if (id < 8192) {
        tloc = id - 4096; R = 1024; C = 4096; csh = 7; src = w1; dst = w1t;
    } else {
        tloc = id - 8192; R = 4096; C = 1024; csh = 5; src = w2; dst = w2t;
    }
    int ty = tloc >> csh, tx = tloc & ((1 << csh) - 1);
    int r0 = ty * 32, c0 = tx * 32;
    __shared__ float t[32][33];
    int tid = threadIdx.x;
#pragma unroll
    for (int i = 0; i < 4; i++) {
        int idx = i * 256 + tid;
        int r = idx >> 5, c = idx & 31;
        t[r][c] = src[(size_t)(r0 + r) * C + c0 + c];
    }
    __syncthreads();
#pragma unroll
    for (int i = 0; i < 4; i++) {
        int idx = i * 256 + tid;
        int rr = idx >> 5, cc = idx & 31;
        dst[(size_t)(c0 + rr) * R + r0 + cc] = f2bf(t[cc][rr]);
    }
}

// ---------------------------------------------------------------------------
// bf16 MFMA GEMM, BK=64, XOR-swizzled LDS, buffering templated:
//   DBUF=0: single 32KB buffer (barrier-stage-barrier-compute). Best when
//           the grid allows >2 blocks/CU (QKV, MLP1) — R9: 111us, 619 TF.
//   DBUF=1: double 64KB buffer, prefetch k+1 before compute k. Best for
//           512-block grids already capped at 2 blocks/CU (O-proj, MLP2):
//           occupancy unchanged, GLD latency hides under compute (R10).
// LDS slot(row, chunk) = row*8 + (chunk ^ (row&7))  [16B slots]:
//   staging keeps 128B-segment coalescing, frag reads conflict-free.
// Grid: 1-D, XCD row-panel swizzle (gy==64): xcd=id&7 owns rows {xcd+8j}.
// C/D layout: col=lane&15, row=quad*4+reg.
// Modes: qkv=1 (fused QKV, V transposed store) / bias+gelu+resid, f32/bf16.
// ---------------------------------------------------------------------------
template<int DBUF>
__global__ __launch_bounds__(256) void gemm_bf16(
    const short* __restrict__ A, int lda,
    const short* __restrict__ Bt, int ldb,
    const float* __restrict__ bias,
    const float* __restrict__ bias2,
    const float* __restrict__ bias3,
    const float* __restrict__ resid,
    float* __restrict__ Cf, short* __restrict__ Cb, short* __restrict__ Cvt,
    int ldc, int K, int act, int qkv, int gx)
{
    __shared__ __align__(16) short sA[(1 + DBUF) * 8192];   // swizzled
    __shared__ __align__(16) short sB[(1 + DBUF) * 8192];
    const int tid = threadIdx.x;
    const int lane = tid & 63, wave = tid >> 6;
    const int quad = lane >> 4, l15 = lane & 15;

    // XCD row-panel swizzle (gy == 64 for all call sites: M = 8192)
    const int id = blockIdx.x;
    const int xcd = id & 7, j = id >> 3;
    const int bx = j % gx, by = xcd + 8 * (j / gx);
    const int bm = by * 128, bn = bx * 128;
    const int wm = (wave >> 1) * 64, wn = (wave & 1) * 64;

    // staging lane decomposition (invariant): row lr, swizzled chunk lc
    const int lr = lane >> 3;            // 0..7 row within an 8-row call
    const int lc = (lane & 7) ^ lr;      // chunk ^ (row&7)
    const int sw = l15 & 7;              // read-side swizzle key

    // global row bases for this thread's 4 staging calls (cid = wave*4+c)
    const short* Ab = A  + (size_t)(bm + wave * 32 + lr) * lda + lc * 8;
    const short* Bb = Bt + (size_t)(bn + wave * 32 + lr) * ldb + lc * 8;

    f32x4 acc[4][4];
#pragma unroll
    for (int i = 0; i < 4; i++)
#pragma unroll
        for (int jj = 0; jj < 4; jj++) acc[i][jj] = (f32x4){0.f, 0.f, 0.f, 0.f};

    const int nk = K >> 6;

    if (DBUF) {
        // prologue: stage tile 0 into buf 0
#pragma unroll
        for (int c = 0; c < 4; c++) {
            int cid = wave * 4 + c;
            GLD16(Ab + (size_t)(c * 8) * lda, &sA[cid * 512]);
            GLD16(Bb + (size_t)(c * 8) * ldb, &sB[cid * 512]);
        }
    }

    for (int ki = 0; ki < nk; ki++) {
        __syncthreads();
        if (DBUF) {
            if (ki + 1 < nk) {
                int k0 = (ki + 1) << 6, nb = (ki + 1) & 1;
#pragma unroll
                for (int c = 0; c < 4; c++) {
                    int cid = wave * 4 + c;
                    GLD16(Ab + (size_t)(c * 8) * lda + k0, &sA[nb * 8192 + cid * 512]);
                    GLD16(Bb + (size_t)(c * 8) * ldb + k0, &sB[nb * 8192 + cid * 512]);
                }
            }
        } else {
            int k0 = ki << 6;
#pragma unroll
            for (int c = 0; c < 4; c++) {
                int cid = wave * 4 + c;
                GLD16(Ab + (size_t)(c * 8) * lda + k0, &sA[cid * 512]);
                GLD16(Bb + (size_t)(c * 8) * ldb + k0, &sB[cid * 512]);
            }
            __syncthreads();
        }
        const short* cA = &sA[DBUF ? (ki & 1) * 8192 : 0];
        const short* cB = &sB[DBUF ? (ki & 1) * 8192 : 0];
#pragma unroll
        for (int ko = 0; ko < 2; ko++) {
            bf16x8 af[4], bfr[4];
#pragma unroll
            for (int mt = 0; mt < 4; mt++) {
                int row = wm + mt * 16 + l15;
                af[mt] = *(const bf16x8*)&cA[(row * 8 + ((ko * 4 + quad) ^ sw)) * 8];
            }
#pragma unroll
            for (int nt = 0; nt < 4; nt++) {
                int row = wn + nt * 16 + l15;
                bfr[nt] = *(const bf16x8*)&cB[(row * 8 + ((ko * 4 + quad) ^ sw)) * 8];
            }
#pragma unroll
            for (int mt = 0; mt < 4; mt++)
#pragma unroll
                for (int nt = 0; nt < 4; nt++)
                    acc[mt][nt] = MFMA16(af[mt], bfr[nt], acc[mt][nt]);
        }
    }

#pragma unroll
    for (int mt = 0; mt < 4; mt++)
#pragma unroll
        for (int nt = 0; nt < 4; nt++) {
            int row0 = bm + wm + mt * 16 + quad * 4;
            int col  = bn + wn + nt * 16 + l15;
            if (qkv) {
                int seg = col >> 10, cloc = col & 1023;
                const float* bp = (seg == 0) ? bias : (seg == 1) ? bias2 : bias3;
                float bval = bp[cloc];
                if (seg == 2) {
                    // V transposed store: page=(b*H+h)*64+d, index = seq pos
                    int bb = row0 >> 10, l0 = row0 & 1023;
                    size_t page = (size_t)(bb * N_HEAD + (cloc >> 6)) * HEAD_D + (cloc & 63);
                    short4v pk = { f2bf(acc[mt][nt][0] + bval), f2bf(acc[mt][nt][1] + bval),
                                   f2bf(acc[mt][nt][2] + bval), f2bf(acc[mt][nt][3] + bval) };
                    *(short4v*)&Cvt[page * SEQ_L + l0] = pk;
                } else {
                    short* dst = Cb + (size_t)seg * ((size_t)N_TOK * D_MODEL);
#pragma unroll
                    for (int r = 0; r < 4; r++)
                        dst[(size_t)(row0 + r) * D_MODEL + cloc] = f2bf(acc[mt][nt][r] + bval);
                }
            } else {
#pragma unroll
                for (int r = 0; r < 4; r++) {
                    int row = row0 + r;
                    float v = acc[mt][nt][r] + bias[col];
                    if (act) v = v / (1.f + __expf(-1.702f * v));   // quick_gelu
                    if (resid) v += resid[(size_t)row * ldc + col];
                    if (Cb) Cb[(size_t)row * ldc + col] = f2bf(v);
                    else    Cf[(size_t)row * ldc + col] = v;
                }
            }
        }
}

// ---------------------------------------------------------------------------
// Flash attention (unchanged from R6 — it works): bf16 MFMA, S^T form,
// K-step=128, m97-style LDS staging, log2-domain softmax, per-wave P slab.
// ---------------------------------------------------------------------------
__global__ __launch_bounds__(256) void attn_kernel(
    const short* __restrict__ Q, const short* __restrict__ Kb,
    const short* __restrict__ Vt, const float* __restrict__ fmask,
    short* __restrict__ O)
{
    __shared__ __align__(16) short sK[8192];        // 16KB: slot=kc*128+key
    __shared__ __align__(16) short sV[8192];        // 16KB: slot=kc2*64+d
    __shared__ __align__(16) short sP[4][16 * 136]; // per-wave [16 q][136]
    __shared__ __align__(16) float sAl[4][20];

    const int g = blockIdx.x;
    const int xcd = g & 7, slot = g >> 3;
    const int qt = slot & 15, bhl = slot >> 4;
    const int bh = xcd * 16 + bhl;
    const int b = bh >> 4, h = bh & 15;

    const int tid = threadIdx.x;
    const int wave = tid >> 6, lane = tid & 63;
    const int quad = lane >> 4, l15 = lane & 15;

    const int qbase = b * SEQ_L + qt * 64;
    const short* qp = Q + (size_t)(qbase + wave * 16 + l15) * D_MODEL + h * HEAD_D + quad * 8;
    bf16x8 qf0 = *(const bf16x8*)qp;
    bf16x8 qf1 = *(const bf16x8*)(qp + 32);

    const short* Kbh = Kb + (size_t)b * SEQ_L * D_MODEL + h * HEAD_D;
    const short* Vbh = Vt + (size_t)(b * N_HEAD + h) * HEAD_D * SEQ_L;
    const float* mk  = fmask + b * SEQ_L;

    f32x4 o4[4];
#pragma unroll
    for (int nt = 0; nt < 4; nt++) o4[nt] = (f32x4){0.f, 0.f, 0.f, 0.f};
    float mrow = -1e30f, lrow = 0.f;     // per-lane: q = l15 of this wave
    short* pslab = &sP[wave][0];         // per-wave private [16 q][136]
    const float CSC = 0.125f * 1.4426950408889634f;   // scale * log2(e)

    for (int kt = 0; kt < SEQ_L / 128; kt++) {
        __syncthreads();   // previous iter's frag reads done
        // ---- stage K-tile + V^T-tile (8 GLD16 per wave, no VGPR data) ----
#pragma unroll
        for (int j = 0; j < 4; j++) {
            int cid = wave * 4 + j;
            int kc = cid >> 1, key0 = (cid & 1) << 6;
            GLD16(Kbh + (size_t)(kt * 128 + key0 + lane) * D_MODEL + kc * 8,
                  &sK[cid * 512]);
            GLD16(Vbh + (size_t)lane * SEQ_L + kt * 128 + cid * 8,
                  &sV[cid * 512]);
        }
        __syncthreads();   // staging complete (vmcnt drained by barrier)

        // ---- mask loads (f32x4, indexed by key=row) ----
        f32x4 mkv[8];
#pragma unroll
        for (int sub = 0; sub < 8; sub++)
            mkv[sub] = *(const f32x4*)&mk[kt * 128 + sub * 16 + quad * 4];

        // ---- S^T = K·Q^T : D[m=key][n=q] ----
        f32x4 s[8];
#pragma unroll
        for (int sub = 0; sub < 8; sub++) {
            bf16x8 kf0 = *(const bf16x8*)&sK[(quad * 128 + sub * 16 + l15) * 8];
            bf16x8 kf1 = *(const bf16x8*)&sK[((quad + 4) * 128 + sub * 16 + l15) * 8];
            s[sub] = (f32x4){0.f, 0.f, 0.f, 0.f};
            s[sub] = MFMA16(kf0, qf0, s[sub]);
            s[sub] = MFMA16(kf1, qf1, s[sub]);
        }
        // ---- scale+mask in one FMA (log2 domain) ----
#pragma unroll
        for (int sub = 0; sub < 8; sub++)
#pragma unroll
            for (int r = 0; r < 4; r++) s[sub][r] = s[sub][r] * CSC + mkv[sub][r];

        // ---- per-lane max over 32 scores + 2 shuffles ----
        f32x4 mx4 = s[0];
#pragma unroll
        for (int sub = 1; sub < 8; sub++)
#pragma unroll
            for (int r = 0; r < 4; r++) mx4[r] = fmaxf(mx4[r], s[sub][r]);
        float pmax = fmaxf(fmaxf(mx4[0], mx4[1]), fmaxf(mx4[2], mx4[3]));
        pmax = fmaxf(pmax, __shfl_xor(pmax, 16));
        pmax = fmaxf(pmax, __shfl_xor(pmax, 32));
        float mnew = fmaxf(mrow, pmax);
        float alpha = EXP2F(mrow - mnew);
        mrow = mnew;
        if (quad == 0) sAl[wave][l15] = alpha;   // broadcast to O rows

        // ---- exp2 + pairwise pack + P writes ----
        float ls = 0.f;
#pragma unroll
        for (int sub = 0; sub < 8; sub++) {
            float p0 = EXP2F(s[sub][0] - mnew);
            float p1 = EXP2F(s[sub][1] - mnew);
            float p2 = EXP2F(s[sub][2] - mnew);
            float p3 = EXP2F(s[sub][3] - mnew);
            ls += (p0 + p1) + (p2 + p3);
            int2v pk = { pack2bf(p0, p1), pack2bf(p2, p3) };
            *(int2v*)&pslab[l15 * 136 + sub * 16 + quad * 4] = pk;
        }
        ls += __shfl_xor(ls, 16);
        ls += __shfl_xor(ls, 32);
        lrow = lrow * alpha + ls;

        // ---- rescale O by alpha (read per-row broadcast) ----
        f32x4 av = *(const f32x4*)&sAl[wave][quad * 4];
#pragma unroll
        for (int nt = 0; nt < 4; nt++)
#pragma unroll
            for (int r = 0; r < 4; r++) o4[nt][r] *= av[r];

        // ---- PV: P A-frags from slab, V B-frags from sV ----
        bf16x8 pf[4];
#pragma unroll
        for (int c = 0; c < 4; c++)
            pf[c] = *(const bf16x8*)&pslab[l15 * 136 + c * 32 + quad * 8];
#pragma unroll
        for (int nt = 0; nt < 4; nt++)
#pragma unroll
            for (int c = 0; c < 4; c++) {
                bf16x8 vfr = *(const bf16x8*)&sV[((c * 4 + quad) * 64 + nt * 16 + l15) * 8];
                o4[nt] = MFMA16(pf[c], vfr, o4[nt]);
            }
    }
    // final 1/l broadcast to O rows
    if (quad == 0) sAl[wave][l15] = 1.f / lrow;
    __syncthreads();
    f32x4 iv = *(const f32x4*)&sAl[wave][quad * 4];
#pragma unroll
    for (int nt = 0; nt < 4; nt++)
#pragma unroll
        for (int r = 0; r < 4; r++)
            O[(size_t)(qbase + wave * 16 + quad * 4 + r) * D_MODEL
              + h * HEAD_D + nt * 16 + l15] = f2bf(o4[nt][r] * iv[r]);
}

// ---------------------------------------------------------------------------
// Launch
// ---------------------------------------------------------------------------
extern "C" void kernel_launch(void* const* d_in, const int* in_sizes, int n_in,
                              void* d_out, int out_size, void* d_ws, size_t ws_size,
                              hipStream_t stream)
{
    const float* x     = (const float*)d_in[0];
    const int*   amask = (const int*)  d_in[1];
    const float* wq    = (const float*)d_in[2];
    const float* bq    = (const float*)d_in[3];
    const float* wk    = (const float*)d_in[4];
    const float* bk    = (const float*)d_in[5];
    const float* wv    = (const float*)d_in[6];
    const float* bv    = (const float*)d_in[7];
    const float* wo    = (const float*)d_in[8];
    const float* bo    = (const float*)d_in[9];
    const float* ln1s  = (const float*)d_in[10];
    const float* ln1b  = (const float*)d_in[11];
    const float* ln2s  = (const float*)d_in[12];
    const float* ln2b  = (const float*)d_in[13];
    const float* w1    = (const float*)d_in[14];
    const float* b1    = (const float*)d_in[15];
    const float* w2    = (const float*)d_in[16];
    const float* b2    = (const float*)d_in[17];
    float* out = (float*)d_out;

    // workspace layout (bytes; peak 104 MB, proven available)
    char* w = (char*)d_ws;
    short* wqkvt = (short*)(w + (size_t)0);          // [3072][1024] bf16, 6MB
    short* wot   = (short*)(w + ((size_t)6  << 20));
    short* w1t   = (short*)(w + ((size_t)8  << 20));
    short* w2t   = (short*)(w + ((size_t)16 << 20));
    short* hb    = (short*)(w + ((size_t)24 << 20)); // LN1 out, later LN2 out
    short* qb    = (short*)(w + ((size_t)40 << 20)); // qb,kbf contiguous:
    short* kbf   = (short*)(w + ((size_t)56 << 20)); //   16MB stride for qkv mode
    short* attnb = (short*)(w + ((size_t)72 << 20));
    short* vtb   = (short*)(w + ((size_t)88 << 20));
    short* ffb   = qb;   // q/k/vt dead by MLP1 (64 MB span 40..104)
    // fmask lives in d_out: free until the O-proj GEMM (step 4) overwrites
    // it, and attn (step 3) has finished reading it by then (same stream).
    float* fmaskb = (float*)d_out;

    dim3 blk(256);

    // prep: six transposes + mask in ONE dispatch
    prep_kernel<<<dim3(12320), blk, 0, stream>>>(wq, wk, wv, wo, w1, w2, amask,
                                                 wqkvt, wot, w1t, w2t, fmaskb);

    // 1) h = LN1(x) -> bf16
    ln_kernel<<<N_TOK, blk, 0, stream>>>(x, ln1s, ln1b, hb);

    // 2) fused QKV GEMM (gx=24, single-buffer: 1536 blocks want occupancy)
    gemm_bf16<0><<<dim3(24 * 64), blk, 0, stream>>>(
        hb, 1024, wqkvt, 1024, bq, bk, bv, nullptr,
        nullptr, qb, vtb, 1024, 1024, 0, 1, 24);

    // 3) flash attention -> attnb (bf16); 1-D grid, XCD swizzle inside
    attn_kernel<<<dim3(2048), blk, 0, stream>>>(qb, kbf, vtb, fmaskb, attnb);

    // 4) out = x + attn @ wo + bo  (512 blocks = 2/CU -> dbuf wins)
    gemm_bf16<1><<<dim3(8 * 64), blk, 0, stream>>>(
        attnb, 1024, wot, 1024, bo, nullptr, nullptr, x,
        out, nullptr, nullptr, 1024, 1024, 0, 0, 8);

    // 5) h = LN2(out) -> bf16
    ln_kernel<<<N_TOK, blk, 0, stream>>>(out, ln2s, ln2b, hb);

    // 6) MLP: MLP1 single-buffer (2048 blocks), MLP2 dbuf (512 blocks)
    gemm_bf16<0><<<dim3(32 * 64), blk, 0, stream>>>(
        hb, 1024, w1t, 1024, b1, nullptr, nullptr, nullptr,
        nullptr, ffb, nullptr, 4096, 1024, 1, 0, 32);
    gemm_bf16<1><<<dim3(8 * 64), blk, 0, stream>>>(
        ffb, 4096, w2t, 4096, b2, nullptr, nullptr, out,
        out, nullptr, nullptr, 1024, 4096, 0, 0, 8);
}

// Round 12
// 536.742 us; speedup vs baseline: 1.3980x; 1.0337x over previous
//
#include <hip/hip_runtime.h>
#include <math.h>

#define D_MODEL 1024
#define N_TOK   8192
#define SEQ_L   1024
#define N_HEAD  16
#define HEAD_D  64
#define FF_DIM  4096

typedef __attribute__((ext_vector_type(8))) short bf16x8;   // 8 bf16 = 4 VGPRs
typedef __attribute__((ext_vector_type(4))) short short4v;
typedef __attribute__((ext_vector_type(2))) int  int2v;
typedef __attribute__((ext_vector_type(4))) float f32x4;

#define MFMA16(a, b, c) __builtin_amdgcn_mfma_f32_16x16x32_bf16((a), (b), (c), 0, 0, 0)

// async global->LDS, 16B per lane; LDS dest = wave-uniform base + lane*16
#define GLD16(gp, lp) __builtin_amdgcn_global_load_lds(                      \
    (const __attribute__((address_space(1))) void*)(gp),                     \
    (__attribute__((address_space(3))) void*)(lp), 16, 0, 0)

#if defined(__has_builtin)
#if __has_builtin(__builtin_amdgcn_exp2f)
#define EXP2F(x) __builtin_amdgcn_exp2f(x)
#else
#define EXP2F(x) exp2f(x)
#endif
#else
#define EXP2F(x) exp2f(x)
#endif

__device__ __forceinline__ short f2bf(float f) {   // fp32 -> bf16 (RNE)
    unsigned u = __float_as_uint(f);
    u += 0x7fffu + ((u >> 16) & 1u);
    return (short)(u >> 16);
}

// pack two fp32 -> two bf16 (round-nearest-up) in one v_perm
__device__ __forceinline__ int pack2bf(float a, float b) {
    unsigned ua = __float_as_uint(a) + 0x8000u;
    unsigned ub = __float_as_uint(b) + 0x8000u;
    return __builtin_amdgcn_perm(ub, ua, 0x07060302u);
}

// ---------------------------------------------------------------------------
// LayerNorm fp32 -> bf16. One block (256 thr) per token.
// ---------------------------------------------------------------------------
__global__ __launch_bounds__(256) void ln_kernel(const float* __restrict__ x,
                                                 const float* __restrict__ g,
                                                 const float* __restrict__ b,
                                                 short* __restrict__ o)
{
    int t = blockIdx.x;
    const float* xr = x + (size_t)t * D_MODEL;
    short* orow = o + (size_t)t * D_MODEL;
    float vals[4];
    float lsum = 0.f, lsq = 0.f;
#pragma unroll
    for (int i = 0; i < 4; i++) {
        float v = xr[threadIdx.x + i * 256];
        vals[i] = v; lsum += v; lsq += v * v;
    }
#pragma unroll
    for (int off = 32; off > 0; off >>= 1) {
        lsum += __shfl_down(lsum, off);
        lsq  += __shfl_down(lsq,  off);
    }
    __shared__ float red[8];
    int wid = threadIdx.x >> 6, lane = threadIdx.x & 63;
    if (lane == 0) { red[wid] = lsum; red[4 + wid] = lsq; }
    __syncthreads();
    if (threadIdx.x == 0) {
        red[0] = red[0] + red[1] + red[2] + red[3];
        red[4] = red[4] + red[5] + red[6] + red[7];
    }
    __syncthreads();
    float mean = red[0] * (1.f / D_MODEL);
    float var  = red[4] * (1.f / D_MODEL) - mean * mean;
    float inv  = rsqrtf(var + 1e-5f);
#pragma unroll
    for (int i = 0; i < 4; i++) {
        int c = threadIdx.x + i * 256;
        orow[c] = f2bf((vals[i] - mean) * inv * g[c] + b[c]);
    }
}

// ---------------------------------------------------------------------------
// Fused prep: six W [K,N] fp32 -> W^T [N,K] bf16 transposes + fp32 mask,
// all in ONE dispatch. Block id ranges select the job; 32x32 tiles.
// fmask target lives in d_out (free until the O-proj GEMM writes it).
// ---------------------------------------------------------------------------
__global__ __launch_bounds__(256) void prep_kernel(
    const float* __restrict__ wq, const float* __restrict__ wk,
    const float* __restrict__ wv, const float* __restrict__ wo,
    const float* __restrict__ w1, const float* __restrict__ w2,
    const int*   __restrict__ amask,
    short* __restrict__ wqkvt, short* __restrict__ wot,
    short* __restrict__ w1t,  short* __restrict__ w2t,
    float* __restrict__ fmask)
{
    int id = blockIdx.x;
    if (id >= 12288) {   // mask job: 32 blocks x 256 = 8192 entries
        int i = (id - 12288) * 256 + threadIdx.x;
        fmask[i] = (amask[i] > 0) ? 0.f : -1e30f;
        return;
    }
    const float* src; short* dst; int R, C, tloc, csh;
    if (id < 4096) {
        int wsel = id >> 10; tloc = id & 1023; R = 1024; C = 1024; csh = 5;
        src = (wsel == 0) ? wq : (wsel == 1) ? wk : (wsel == 2) ? wv : wo;
        dst = (wsel == 3) ? wot : (wqkvt + (size_t)wsel * 1024 * 1024);
    } else if (id < 8192) {
        tloc = id - 4096; R = 1024; C = 4096; csh = 7; src = w1; dst = w1t;
    } else {
        tloc = id - 8192; R = 4096; C = 1024; csh = 5; src = w2; dst = w2t;
    }
    int ty = tloc >> csh, tx = tloc & ((1 << csh) - 1);
    int r0 = ty * 32, c0 = tx * 32;
    __shared__ float t[32][33];
    int tid = threadIdx.x;
#pragma unroll
    for (int i = 0; i < 4; i++) {
        int idx = i * 256 + tid;
        int r = idx >> 5, c = idx & 31;
        t[r][c] = src[(size_t)(r0 + r) * C + c0 + c];
    }
    __syncthreads();
#pragma unroll
    for (int i = 0; i < 4; i++) {
        int idx = i * 256 + tid;
        int rr = idx >> 5, cc = idx & 31;
        dst[(size_t)(c0 + rr) * R + r0 + cc] = f2bf(t[cc][rr]);
    }
}

// ---------------------------------------------------------------------------
// bf16 MFMA GEMM, BK=64, XOR-swizzled LDS, buffering templated:
//   DBUF=0: single 32KB buffer — best when grid allows >2 blocks/CU.
//   DBUF=1: double 64KB buffer, prefetch k+1 before compute k — best for
//           512-block grids already capped at 2 blocks/CU (R10/R11 A/B).
// LDS slot(row, chunk) = row*8 + (chunk ^ (row&7))  [16B slots].
// Grid: 1-D, XCD row-panel swizzle (gy==64): xcd=id&7 owns rows {xcd+8j}.
// C/D layout: col=lane&15, row=quad*4+reg.
// ---------------------------------------------------------------------------
template<int DBUF>
__global__ __launch_bounds__(256) void gemm_bf16(
    const short* __restrict__ A, int lda,
    const short* __restrict__ Bt, int ldb,
    const float* __restrict__ bias,
    const float* __restrict__ bias2,
    const float* __restrict__ bias3,
    const float* __restrict__ resid,
    float* __restrict__ Cf, short* __restrict__ Cb, short* __restrict__ Cvt,
    int ldc, int K, int act, int qkv, int gx)
{
    __shared__ __align__(16) short sA[(1 + DBUF) * 8192];   // swizzled
    __shared__ __align__(16) short sB[(1 + DBUF) * 8192];
    const int tid = threadIdx.x;
    const int lane = tid & 63, wave = tid >> 6;
    const int quad = lane >> 4, l15 = lane & 15;

    // XCD row-panel swizzle (gy == 64 for all call sites: M = 8192)
    const int id = blockIdx.x;
    const int xcd = id & 7, j = id >> 3;
    const int bx = j % gx, by = xcd + 8 * (j / gx);
    const int bm = by * 128, bn = bx * 128;
    const int wm = (wave >> 1) * 64, wn = (wave & 1) * 64;

    // staging lane decomposition (invariant): row lr, swizzled chunk lc
    const int lr = lane >> 3;            // 0..7 row within an 8-row call
    const int lc = (lane & 7) ^ lr;      // chunk ^ (row&7)
    const int sw = l15 & 7;              // read-side swizzle key

    // global row bases for this thread's 4 staging calls (cid = wave*4+c)
    const short* Ab = A  + (size_t)(bm + wave * 32 + lr) * lda + lc * 8;
    const short* Bb = Bt + (size_t)(bn + wave * 32 + lr) * ldb + lc * 8;

    f32x4 acc[4][4];
#pragma unroll
    for (int i = 0; i < 4; i++)
#pragma unroll
        for (int jj = 0; jj < 4; jj++) acc[i][jj] = (f32x4){0.f, 0.f, 0.f, 0.f};

    const int nk = K >> 6;

    if (DBUF) {
#pragma unroll
        for (int c = 0; c < 4; c++) {
            int cid = wave * 4 + c;
            GLD16(Ab + (size_t)(c * 8) * lda, &sA[cid * 512]);
            GLD16(Bb + (size_t)(c * 8) * ldb, &sB[cid * 512]);
        }
    }

    for (int ki = 0; ki < nk; ki++) {
        __syncthreads();
        if (DBUF) {
            if (ki + 1 < nk) {
                int k0 = (ki + 1) << 6, nb = (ki + 1) & 1;
#pragma unroll
                for (int c = 0; c < 4; c++) {
                    int cid = wave * 4 + c;
                    GLD16(Ab + (size_t)(c * 8) * lda + k0, &sA[nb * 8192 + cid * 512]);
                    GLD16(Bb + (size_t)(c * 8) * ldb + k0, &sB[nb * 8192 + cid * 512]);
                }
            }
        } else {
            int k0 = ki << 6;
#pragma unroll
            for (int c = 0; c < 4; c++) {
                int cid = wave * 4 + c;
                GLD16(Ab + (size_t)(c * 8) * lda + k0, &sA[cid * 512]);
                GLD16(Bb + (size_t)(c * 8) * ldb + k0, &sB[cid * 512]);
            }
            __syncthreads();
        }
        const short* cA = &sA[DBUF ? (ki & 1) * 8192 : 0];
        const short* cB = &sB[DBUF ? (ki & 1) * 8192 : 0];
#pragma unroll
        for (int ko = 0; ko < 2; ko++) {
            bf16x8 af[4], bfr[4];
#pragma unroll
            for (int mt = 0; mt < 4; mt++) {
                int row = wm + mt * 16 + l15;
                af[mt] = *(const bf16x8*)&cA[(row * 8 + ((ko * 4 + quad) ^ sw)) * 8];
            }
#pragma unroll
            for (int nt = 0; nt < 4; nt++) {
                int row = wn + nt * 16 + l15;
                bfr[nt] = *(const bf16x8*)&cB[(row * 8 + ((ko * 4 + quad) ^ sw)) * 8];
            }
#pragma unroll
            for (int mt = 0; mt < 4; mt++)
#pragma unroll
                for (int nt = 0; nt < 4; nt++)
                    acc[mt][nt] = MFMA16(af[mt], bfr[nt], acc[mt][nt]);
        }
    }

#pragma unroll
    for (int mt = 0; mt < 4; mt++)
#pragma unroll
        for (int nt = 0; nt < 4; nt++) {
            int row0 = bm + wm + mt * 16 + quad * 4;
            int col  = bn + wn + nt * 16 + l15;
            if (qkv) {
                int seg = col >> 10, cloc = col & 1023;
                const float* bp = (seg == 0) ? bias : (seg == 1) ? bias2 : bias3;
                float bval = bp[cloc];
                if (seg == 2) {
                    // V transposed store: page=(b*H+h)*64+d, index = seq pos
                    int bb = row0 >> 10, l0 = row0 & 1023;
                    size_t page = (size_t)(bb * N_HEAD + (cloc >> 6)) * HEAD_D + (cloc & 63);
                    short4v pk = { f2bf(acc[mt][nt][0] + bval), f2bf(acc[mt][nt][1] + bval),
                                   f2bf(acc[mt][nt][2] + bval), f2bf(acc[mt][nt][3] + bval) };
                    *(short4v*)&Cvt[page * SEQ_L + l0] = pk;
                } else {
                    short* dst = Cb + (size_t)seg * ((size_t)N_TOK * D_MODEL);
#pragma unroll
                    for (int r = 0; r < 4; r++)
                        dst[(size_t)(row0 + r) * D_MODEL + cloc] = f2bf(acc[mt][nt][r] + bval);
                }
            } else {
#pragma unroll
                for (int r = 0; r < 4; r++) {
                    int row = row0 + r;
                    float v = acc[mt][nt][r] + bias[col];
                    if (act) v = v / (1.f + __expf(-1.702f * v));   // quick_gelu
                    if (resid) v += resid[(size_t)row * ldc + col];
                    if (Cb) Cb[(size_t)row * ldc + col] = f2bf(v);
                    else    Cf[(size_t)row * ldc + col] = v;
                }
            }
        }
}

// ---------------------------------------------------------------------------
// Flash attention, 128 q-rows/block: each wave owns 32 q as two 16-row
// halves that REUSE the same staged K/V tiles -> 64 MFMAs per iteration
// for the same per-iter overhead (2 barriers, staging, softmax chain).
// S^T form (lane&15 = q), log2-domain softmax, per-wave P slab, m97-style
// LDS staging. Grid 1024 = 8 XCD x (8 qt x 16 bh).
// ---------------------------------------------------------------------------
__global__ __launch_bounds__(256) void attn_kernel(
    const short* __restrict__ Q, const short* __restrict__ Kb,
    const short* __restrict__ Vt, const float* __restrict__ fmask,
    short* __restrict__ O)
{
    __shared__ __align__(16) short sK[8192];        // 16KB: slot=kc*128+key
    __shared__ __align__(16) short sV[8192];        // 16KB: slot=kc2*64+d
    __shared__ __align__(16) short sP[4][32 * 136]; // per-wave [32 q][136]
    __shared__ __align__(16) float sAl[4][2][20];

    const int g = blockIdx.x;
    const int xcd = g & 7, slot = g >> 3;
    const int qt = slot & 7, bhl = slot >> 3;
    const int bh = xcd * 16 + bhl;
    const int b = bh >> 4, h = bh & 15;

    const int tid = threadIdx.x;
    const int wave = tid >> 6, lane = tid & 63;
    const int quad = lane >> 4, l15 = lane & 15;

    const int qbase = b * SEQ_L + qt * 128;
    bf16x8 qf[2][2];
#pragma unroll
    for (int qh = 0; qh < 2; qh++) {
        const short* qp = Q + (size_t)(qbase + wave * 32 + qh * 16 + l15) * D_MODEL
                        + h * HEAD_D + quad * 8;
        qf[qh][0] = *(const bf16x8*)qp;
        qf[qh][1] = *(const bf16x8*)(qp + 32);
    }

    const short* Kbh = Kb + (size_t)b * SEQ_L * D_MODEL + h * HEAD_D;
    const short* Vbh = Vt + (size_t)(b * N_HEAD + h) * HEAD_D * SEQ_L;
    const float* mk  = fmask + b * SEQ_L;

    f32x4 o4[2][4];
#pragma unroll
    for (int qh = 0; qh < 2; qh++)
#pragma unroll
        for (int nt = 0; nt < 4; nt++) o4[qh][nt] = (f32x4){0.f, 0.f, 0.f, 0.f};
    float mrow[2] = {-1e30f, -1e30f}, lrow[2] = {0.f, 0.f};
    short* pslab = &sP[wave][0];         // per-wave private [32 q][136]
    const float CSC = 0.125f * 1.4426950408889634f;   // scale * log2(e)

    for (int kt = 0; kt < SEQ_L / 128; kt++) {
        __syncthreads();   // previous iter's frag reads done
        // ---- stage K-tile + V^T-tile (8 GLD16 per wave, no VGPR data) ----
#pragma unroll
        for (int j = 0; j < 4; j++) {
            int cid = wave * 4 + j;
            int kc = cid >> 1, key0 = (cid & 1) << 6;
            GLD16(Kbh + (size_t)(kt * 128 + key0 + lane) * D_MODEL + kc * 8,
                  &sK[cid * 512]);
            GLD16(Vbh + (size_t)lane * SEQ_L + kt * 128 + cid * 8,
                  &sV[cid * 512]);
        }
        __syncthreads();   // staging complete (vmcnt drained by barrier)

        // ---- mask loads (f32x4, indexed by key=row) ----
        f32x4 mkv[8];
#pragma unroll
        for (int sub = 0; sub < 8; sub++)
            mkv[sub] = *(const f32x4*)&mk[kt * 128 + sub * 16 + quad * 4];

        // ---- S^T = K·Q^T for both q-halves (K frags reused) ----
        f32x4 s[8][2];
#pragma unroll
        for (int sub = 0; sub < 8; sub++) {
            bf16x8 kf0 = *(const bf16x8*)&sK[(quad * 128 + sub * 16 + l15) * 8];
            bf16x8 kf1 = *(const bf16x8*)&sK[((quad + 4) * 128 + sub * 16 + l15) * 8];
#pragma unroll
            for (int qh = 0; qh < 2; qh++) {
                s[sub][qh] = (f32x4){0.f, 0.f, 0.f, 0.f};
                s[sub][qh] = MFMA16(kf0, qf[qh][0], s[sub][qh]);
                s[sub][qh] = MFMA16(kf1, qf[qh][1], s[sub][qh]);
            }
        }
        // ---- scale+mask, max, exp2, pack, l-sum — two independent chains ----
        float alpha[2];
#pragma unroll
        for (int qh = 0; qh < 2; qh++) {
#pragma unroll
            for (int sub = 0; sub < 8; sub++)
#pragma unroll
                for (int r = 0; r < 4; r++)
                    s[sub][qh][r] = s[sub][qh][r] * CSC + mkv[sub][r];
            f32x4 mx4 = s[0][qh];
#pragma unroll
            for (int sub = 1; sub < 8; sub++)
#pragma unroll
                for (int r = 0; r < 4; r++) mx4[r] = fmaxf(mx4[r], s[sub][qh][r]);
            float pmax = fmaxf(fmaxf(mx4[0], mx4[1]), fmaxf(mx4[2], mx4[3]));
            pmax = fmaxf(pmax, __shfl_xor(pmax, 16));
            pmax = fmaxf(pmax, __shfl_xor(pmax, 32));
            float mnew = fmaxf(mrow[qh], pmax);
            alpha[qh] = EXP2F(mrow[qh] - mnew);
            mrow[qh] = mnew;
            if (quad == 0) sAl[wave][qh][l15] = alpha[qh];

            float ls = 0.f;
#pragma unroll
            for (int sub = 0; sub < 8; sub++) {
                float p0 = EXP2F(s[sub][qh][0] - mnew);
                float p1 = EXP2F(s[sub][qh][1] - mnew);
                float p2 = EXP2F(s[sub][qh][2] - mnew);
                float p3 = EXP2F(s[sub][qh][3] - mnew);
                ls += (p0 + p1) + (p2 + p3);
                int2v pk = { pack2bf(p0, p1), pack2bf(p2, p3) };
                *(int2v*)&pslab[(qh * 16 + l15) * 136 + sub * 16 + quad * 4] = pk;
            }
            ls += __shfl_xor(ls, 16);
            ls += __shfl_xor(ls, 32);
            lrow[qh] = lrow[qh] * alpha[qh] + ls;
        }

        // ---- rescale O by alpha (per-row broadcast) ----
#pragma unroll
        for (int qh = 0; qh < 2; qh++) {
            f32x4 av = *(const f32x4*)&sAl[wave][qh][quad * 4];
#pragma unroll
            for (int nt = 0; nt < 4; nt++)
#pragma unroll
                for (int r = 0; r < 4; r++) o4[qh][nt][r] *= av[r];
        }

        // ---- PV: P A-frags per half, V B-frags shared ----
        bf16x8 pf[2][4];
#pragma unroll
        for (int qh = 0; qh < 2; qh++)
#pragma unroll
            for (int c = 0; c < 4; c++)
                pf[qh][c] = *(const bf16x8*)&pslab[(qh * 16 + l15) * 136 + c * 32 + quad * 8];
#pragma unroll
        for (int nt = 0; nt < 4; nt++)
#pragma unroll
            for (int c = 0; c < 4; c++) {
                bf16x8 vfr = *(const bf16x8*)&sV[((c * 4 + quad) * 64 + nt * 16 + l15) * 8];
                o4[0][nt] = MFMA16(pf[0][c], vfr, o4[0][nt]);
                o4[1][nt] = MFMA16(pf[1][c], vfr, o4[1][nt]);
            }
    }
    // final 1/l broadcast to O rows
    if (quad == 0) {
        sAl[wave][0][l15] = 1.f / lrow[0];
        sAl[wave][1][l15] = 1.f / lrow[1];
    }
    __syncthreads();
#pragma unroll
    for (int qh = 0; qh < 2; qh++) {
        f32x4 iv = *(const f32x4*)&sAl[wave][qh][quad * 4];
#pragma unroll
        for (int nt = 0; nt < 4; nt++)
#pragma unroll
            for (int r = 0; r < 4; r++)
                O[(size_t)(qbase + wave * 32 + qh * 16 + quad * 4 + r) * D_MODEL
                  + h * HEAD_D + nt * 16 + l15] = f2bf(o4[qh][nt][r] * iv[r]);
    }
}

// ---------------------------------------------------------------------------
// Launch
// ---------------------------------------------------------------------------
extern "C" void kernel_launch(void* const* d_in, const int* in_sizes, int n_in,
                              void* d_out, int out_size, void* d_ws, size_t ws_size,
                              hipStream_t stream)
{
    const float* x     = (const float*)d_in[0];
    const int*   amask = (const int*)  d_in[1];
    const float* wq    = (const float*)d_in[2];
    const float* bq    = (const float*)d_in[3];
    const float* wk    = (const float*)d_in[4];
    const float* bk    = (const float*)d_in[5];
    const float* wv    = (const float*)d_in[6];
    const float* bv    = (const float*)d_in[7];
    const float* wo    = (const float*)d_in[8];
    const float* bo    = (const float*)d_in[9];
    const float* ln1s  = (const float*)d_in[10];
    const float* ln1b  = (const float*)d_in[11];
    const float* ln2s  = (const float*)d_in[12];
    const float* ln2b  = (const float*)d_in[13];
    const float* w1    = (const float*)d_in[14];
    const float* b1    = (const float*)d_in[15];
    const float* w2    = (const float*)d_in[16];
    const float* b2    = (const float*)d_in[17];
    float* out = (float*)d_out;

    // workspace layout (bytes; peak 104 MB, proven available)
    char* w = (char*)d_ws;
    short* wqkvt = (short*)(w + (size_t)0);          // [3072][1024] bf16, 6MB
    short* wot   = (short*)(w + ((size_t)6  << 20));
    short* w1t   = (short*)(w + ((size_t)8  << 20));
    short* w2t   = (short*)(w + ((size_t)16 << 20));
    short* hb    = (short*)(w + ((size_t)24 << 20)); // LN1 out, later LN2 out
    short* qb    = (short*)(w + ((size_t)40 << 20)); // qb,kbf contiguous:
    short* kbf   = (short*)(w + ((size_t)56 << 20)); //   16MB stride for qkv mode
    short* attnb = (short*)(w + ((size_t)72 << 20));
    short* vtb   = (short*)(w + ((size_t)88 << 20));
    short* ffb   = qb;   // q/k/vt dead by MLP1 (64 MB span 40..104)
    // fmask lives in d_out: free until the O-proj GEMM (step 4) overwrites
    // it, and attn (step 3) has finished reading it by then (same stream).
    float* fmaskb = (float*)d_out;

    dim3 blk(256);

    // prep: six transposes + mask in ONE dispatch
    prep_kernel<<<dim3(12320), blk, 0, stream>>>(wq, wk, wv, wo, w1, w2, amask,
                                                 wqkvt, wot, w1t, w2t, fmaskb);

    // 1) h = LN1(x) -> bf16
    ln_kernel<<<N_TOK, blk, 0, stream>>>(x, ln1s, ln1b, hb);

    // 2) fused QKV GEMM (gx=24, single-buffer: 1536 blocks want occupancy)
    gemm_bf16<0><<<dim3(24 * 64), blk, 0, stream>>>(
        hb, 1024, wqkvt, 1024, bq, bk, bv, nullptr,
        nullptr, qb, vtb, 1024, 1024, 0, 1, 24);

    // 3) flash attention -> attnb (bf16); 1024 blocks, 128 q-rows each
    attn_kernel<<<dim3(1024), blk, 0, stream>>>(qb, kbf, vtb, fmaskb, attnb);

    // 4) out = x + attn @ wo + bo  (512 blocks = 2/CU -> dbuf wins)
    gemm_bf16<1><<<dim3(8 * 64), blk, 0, stream>>>(
        attnb, 1024, wot, 1024, bo, nullptr, nullptr, x,
        out, nullptr, nullptr, 1024, 1024, 0, 0, 8);

    // 5) h = LN2(out) -> bf16
    ln_kernel<<<N_TOK, blk, 0, stream>>>(out, ln2s, ln2b, hb);

    // 6) MLP: MLP1 single-buffer (2048 blocks), MLP2 dbuf (512 blocks)
    gemm_bf16<0><<<dim3(32 * 64), blk, 0, stream>>>(
        hb, 1024, w1t, 1024, b1, nullptr, nullptr, nullptr,
        nullptr, ffb, nullptr, 4096, 1024, 1, 0, 32);
    gemm_bf16<1><<<dim3(8 * 64), blk, 0, stream>>>(
        ffb, 4096, w2t, 4096, b2, nullptr, nullptr, out,
        out, nullptr, nullptr, 1024, 4096, 0, 0, 8);
}